// Round 18
// baseline (235.524 us; speedup 1.0000x reference)
//
#include <hip/hip_runtime.h>

// Problem constants
#define NPG   39
#define NGRAPH 8192
#define EPG   312           // input edges per graph
#define EDG   351           // + 39 self loops
#define E0    2555904       // total input edges (8192*312)
#define FDIM  4560
#define KP    4608          // padded K for bf16 GEMM (multiple of 128)

typedef __bf16 bf16x8 __attribute__((ext_vector_type(8)));
typedef float  f32x4  __attribute__((ext_vector_type(4)));

__device__ __forceinline__ unsigned short f2b(float f) {
  unsigned int u = __float_as_uint(f);
  u += 0x7fffu + ((u >> 16) & 1u);            // RNE to bf16
  return (unsigned short)(u >> 16);
}
__device__ __forceinline__ unsigned int pk2(float lo, float hi) {
  return (unsigned int)f2b(lo) | ((unsigned int)f2b(hi) << 16);
}
__device__ __forceinline__ float b2f(unsigned short u) {
  return __uint_as_float((unsigned int)u << 16);
}
// wave-level "barrier": single wave per workgroup -> LDS drain + compiler fence
__device__ __forceinline__ void wsync() {
  asm volatile("s_waitcnt lgkmcnt(0)" ::: "memory");
}
// drain global stores (f_row RAW across layers, same CU)
__device__ __forceinline__ void gsync() {
  asm volatile("s_waitcnt vmcnt(0) lgkmcnt(0)" ::: "memory");
}

// =================== per-graph LDS (one wave per graph) ===================
__shared__ alignas(16) unsigned short Htb[32 * 64];      // 4096 B
__shared__ alignas(16) unsigned short alf16[40 * 64];    // 5120 B
__shared__ float sn[40];                                 // src attn scalars (alias: cnt)
__shared__ float dn[48];                                 // d-dot, then 1/den (pad 48)
__shared__ unsigned char csr_src[EDG + 1];
__shared__ unsigned short csr_ptr[NPG + 1];

// ======================= fused GAT layer (per wave) =======================
// INSRC: 0 = x register (L1), 1 = alf16 (prev layer staged), 2 = f_row.
// OUTDST: 0 = Htb staging (L2 halves, L4), 1 = alf16 staging (-> next layer).
template<int Fi, int Fo, int KPAD, int KT1, int NT, int HALVES,
         int DT, int SCOL, int DCOL, int INSRC, int OUTDST, bool GSYNC>
__device__ __forceinline__ void layerM(float x0,
                                       const unsigned short* __restrict__ Wb,
                                       const float* __restrict__ W1,
                                       const float* __restrict__ as1,
                                       const float* __restrict__ ad1,
                                       const float* __restrict__ bias,
                                       unsigned short* __restrict__ f_row,
                                       int in_off, int res_off, int out_off,
                                       int lane) {
  constexpr int NTH = NT / HALVES;
  constexpr int RMASK = (Fi >= 16) ? (Fi / 8 - 1) : 0;  // alf16 input swizzle
  constexpr int WMASK = (Fo >= 16) ? (Fo / 8 - 1) : 0;  // alf16 output swizzle
  constexpr int VW  = (HALVES == 2) ? 32 : Fo;          // Htb staging row width
  constexpr bool SWZST = (VW == 32);
  const int r15 = lane & 15, g = lane >> 4;
  const f32x4 z = {0.f, 0.f, 0.f, 0.f};
  const uint4 z4 = {0u, 0u, 0u, 0u};

  f32x4 c1[3][NT];                               // feature tiles (Fi>1)

  // ---------------- P1: c1 tiles + attention dot columns ----------------
  if constexpr (Fi == 1) {
    float was = 0.f, wad = 0.f;
#pragma unroll
    for (int o = 0; o < 8; ++o) { float w = W1[o]; was += w * as1[o]; wad += w * ad1[o]; }
    if (lane < NPG) {
      sn[lane] = x0 * was; dn[lane] = x0 * wad;
#pragma unroll
      for (int o = 0; o < 8; ++o) {              // Ht written directly
        int idx = o * 64 + ((((lane >> 3) ^ (o & 7)) << 3)) + (lane & 7);
        Htb[idx] = f2b(x0 * W1[o]);
      }
    }
  } else {
    if constexpr (GSYNC) gsync();                // L2's f flush must land
    f32x4 cd[3];
#pragma unroll
    for (int mt = 0; mt < 3; ++mt) cd[mt] = z;
#pragma unroll
    for (int mt = 0; mt < 3; ++mt)
#pragma unroll
      for (int nt = 0; nt < NT; ++nt) c1[mt][nt] = z;
    __builtin_amdgcn_s_setprio(1);
#pragma unroll
    for (int kt = 0; kt < KT1; ++kt) {
      bf16x8 aF[3];
#pragma unroll
      for (int mt = 0; mt < 3; ++mt) {
        int row = 16 * mt + r15;
        if constexpr (INSRC == 2) {
          row = (row > 39) ? 39 : row;           // never read uninit f bytes
          aF[mt] = *(const bf16x8*)&f_row[in_off + row * Fi + kt * 32 + g * 8];
        } else {
          aF[mt] = *(const bf16x8*)&alf16[row * Fi + (((kt * 4 + g) ^ (row & RMASK)) << 3)];
        }
      }
      if constexpr (DT >= NT) {                  // separate dot tile
        bf16x8 bD = *(const bf16x8*)&Wb[(16 * DT + r15) * KPAD + kt * 32 + g * 8];
#pragma unroll
        for (int mt = 0; mt < 3; ++mt)
          cd[mt] = __builtin_amdgcn_mfma_f32_16x16x32_bf16(aF[mt], bD, cd[mt], 0, 0, 0);
      }
#pragma unroll
      for (int nt = 0; nt < NT; ++nt) {
        bf16x8 bW = *(const bf16x8*)&Wb[(16 * nt + r15) * KPAD + kt * 32 + g * 8];
#pragma unroll
        for (int mt = 0; mt < 3; ++mt)
          c1[mt][nt] = __builtin_amdgcn_mfma_f32_16x16x32_bf16(aF[mt], bW, c1[mt][nt], 0, 0, 0);
      }
    }
    __builtin_amdgcn_s_setprio(0);
#pragma unroll
    for (int mt = 0; mt < 3; ++mt)
#pragma unroll
      for (int v = 0; v < 4; ++v) {
        float base = (DT >= NT) ? cd[mt][v] : c1[mt][DT][v];
        float t = base + __shfl_xor(base, 4);    // hi + lo column
        int r = 16 * mt + g * 4 + v;
        if (r15 == SCOL && r < NPG) sn[r] = t;
        if (r15 == DCOL && r < NPG) dn[r] = t;
      }
  }
  wsync();                                       // input consumed; sn/dn visible

  // ---- wave-global softmax shift (softmax is shift-invariant; lrelu is
  //      monotone so mg = lrelu(max sn + max dn) >= every e) ----
  float svm = (lane < NPG) ? sn[lane] : -3.4e38f;
  float dvm = (lane < NPG) ? dn[lane] : -3.4e38f;
#pragma unroll
  for (int st = 1; st < 64; st <<= 1) {
    svm = fmaxf(svm, __shfl_xor(svm, st));
    dvm = fmaxf(dvm, __shfl_xor(dvm, st));
  }
  float mg = svm + dvm;
  mg = (mg >= 0.f) ? mg : 0.2f * mg;

  // ---- zero alpha (deferred: input in alf16 already consumed into c1) ----
#pragma unroll
  for (int i = 0; i < 5; ++i) *(uint4*)&alf16[lane * 8 + i * 512] = z4;
  wsync();

  // ---- P3: per-dst softmax (single pass; global shift mg) ----
  if (lane < NPG) {
    int rs = csr_ptr[lane], re = csr_ptr[lane + 1];
    float dv = dn[lane];
    float den = 0.f;
    for (int k = rs; k < re; ++k) {
      int s = csr_src[k];
      float e = sn[s] + dv;
      e = (e >= 0.f) ? e : 0.2f * e;
      float w = __expf(e - mg);
      int idx = lane * 64 + ((((s >> 3) ^ (lane & 7)) << 3)) + (s & 7);
      float cur = b2f(alf16[idx]);               // duplicate edges accumulate
      unsigned short nb = f2b(cur + w);
      alf16[idx] = nb;
      den += b2f(nb) - cur;                      // den == sum of stored values
    }
    dn[lane] = 1.f / (den + 1e-16f);
  }
  wsync();

  // ---------------- P4: Out = alpha @ H via MFMA, per half ----------------
  float invr[3][4];
#pragma unroll
  for (int mt = 0; mt < 3; ++mt)
#pragma unroll
    for (int v = 0; v < 4; ++v) invr[mt][v] = dn[16 * mt + g * 4 + v];

  float pool_[NT];
#pragma unroll
  for (int s = 0; s < NT; ++s) pool_[s] = 0.f;

#pragma unroll
  for (int h = 0; h < HALVES; ++h) {
    const int colbase = (HALVES == 2) ? 32 * h : 0;
    if constexpr (Fi > 1) {                      // Ht from c1 registers
#pragma unroll
      for (int tl = 0; tl < NTH; ++tl) {
        int p = r15 + 16 * tl;
#pragma unroll
        for (int mt = 0; mt < 3; ++mt) {
          uint2 w;
          w.x = pk2(c1[mt][h * NTH + tl][0], c1[mt][h * NTH + tl][1]);
          w.y = pk2(c1[mt][h * NTH + tl][2], c1[mt][h * NTH + tl][3]);
          int idx = p * 64 + (((2 * mt + (g >> 1)) ^ (p & 7)) << 3) + (g & 1) * 4;
          *(uint2*)&Htb[idx] = w;
        }
      }
    }
    wsync();
    // alpha @ Ht
    f32x4 c2[3][NTH];
#pragma unroll
    for (int mt = 0; mt < 3; ++mt)
#pragma unroll
      for (int tl = 0; tl < NTH; ++tl) c2[mt][tl] = z;
    __builtin_amdgcn_s_setprio(1);
#pragma unroll
    for (int kt = 0; kt < 2; ++kt) {
      bf16x8 aA[3];
#pragma unroll
      for (int mt = 0; mt < 3; ++mt) {
        int row = 16 * mt + r15;
        aA[mt] = *(const bf16x8*)&alf16[row * 64 + ((((4 * kt + g) ^ (row & 7))) << 3)];
      }
#pragma unroll
      for (int tl = 0; tl < NTH; ++tl) {
        int p = r15 + 16 * tl;
        bf16x8 bH = *(const bf16x8*)&Htb[p * 64 + ((((4 * kt + g) ^ (p & 7))) << 3)];
#pragma unroll
        for (int mt = 0; mt < 3; ++mt)
          c2[mt][tl] = __builtin_amdgcn_mfma_f32_16x16x32_bf16(aA[mt], bH, c2[mt][tl], 0, 0, 0);
      }
    }
    __builtin_amdgcn_s_setprio(0);
    // epilogue: 1/den, bias, relu, stage (alpha/Ht dead post-c2), pool
#pragma unroll
    for (int tl = 0; tl < NTH; ++tl) {
      int c = r15 + 16 * (h * NTH + tl);
      float bv = (c < Fo) ? bias[c] : 0.f;
#pragma unroll
      for (int mt = 0; mt < 3; ++mt)
#pragma unroll
        for (int v = 0; v < 4; ++v) {
          int r = 16 * mt + g * 4 + v;
          float val = fmaxf(c2[mt][tl][v] * invr[mt][v] + bv, 0.f);
          if (r < NPG && c < Fo) {
            if constexpr (OUTDST == 1) {
              alf16[r * Fo + ((((c >> 3) ^ (r & WMASK)) << 3) | (c & 7))] = f2b(val);
            } else {
              int sc = c - colbase;
              int so = SWZST ? ((sc >> 3) ^ ((r >> 2) & 3)) : (sc >> 3);
              Htb[r * VW + (so << 3) + (sc & 7)] = f2b(val);
            }
            pool_[h * NTH + tl] = fmaxf(pool_[h * NTH + tl], val);
          }
        }
    }
    wsync();                                     // staging visible cross-lane

    // ---- residual flush: staging -> f_row, full 16B lines ----
    if constexpr (OUTDST == 1) {
      if constexpr (Fo == 8) {
        if (lane < NPG)
          *(uint4*)&f_row[res_off + lane * 8] = *(const uint4*)&alf16[lane * 8];
      } else {                                   // Fo == 32
        for (int j = lane; j < NPG * 4; j += 64) {
          int r = j >> 2, o = j & 3;
          *(uint4*)&f_row[res_off + r * 32 + 8 * o] =
              *(const uint4*)&alf16[r * 32 + ((o ^ (r & 3)) << 3)];
        }
      }
    } else if constexpr (Fo == 9) {
      for (int j = lane; j < 43; j += 64)
        *(uint4*)&f_row[res_off + j * 8] = *(const uint4*)&Htb[j * 8];
      if (lane < 7) f_row[res_off + 344 + lane] = Htb[344 + lane];
    } else {                                     // L2 halves (VW=32)
      for (int j = lane; j < NPG * 4; j += 64) {
        int r = j >> 2, o = j & 3;
        int so = o ^ ((r >> 2) & 3);
        *(uint4*)&f_row[res_off + r * Fo + colbase + 8 * o] =
            *(const uint4*)&Htb[r * VW + 8 * so];
      }
    }
    wsync();                                     // before next half's Ht writes
  }

  // ---- P5: per-graph max pool (cross-lane over row groups) ----
#pragma unroll
  for (int s = 0; s < NT; ++s) {
    float pv = pool_[s];
    pv = fmaxf(pv, __shfl_xor(pv, 16));
    pv = fmaxf(pv, __shfl_xor(pv, 32));
    int c = r15 + 16 * s;
    if (g == 0 && c < Fo) f_row[out_off + c] = f2b(pv);
  }
}

// =========================== fused GAT kernel ===========================
__global__ __launch_bounds__(64, 4) void gat_fused(
    const float* __restrict__ x, const int* __restrict__ ei,
    const float* __restrict__ W1, const float* __restrict__ as1, const float* __restrict__ ad1,
    const float* __restrict__ b1, const float* __restrict__ b2,
    const float* __restrict__ b3, const float* __restrict__ b4,
    const unsigned short* __restrict__ Wb,
    unsigned short* __restrict__ f) {
  const int b = blockIdx.x;
  const int lane = threadIdx.x;                    // one wave per graph
  const int base = b * NPG;
  const int* srcg = ei + (size_t)b * EPG;
  const int* dstg = ei + E0 + (size_t)b * EPG;
  unsigned short* f_row = f + (size_t)b * KP;
  int* cnt = (int*)sn;                             // alias: sn unused until layers
  const uint4 z4 = {0u, 0u, 0u, 0u};

  // zero Ht once (finite content guarantee for never-written node-cols 48-63)
#pragma unroll
  for (int i = 0; i < 4; ++i) *(uint4*)&Htb[lane * 8 + i * 512] = z4;

  // x load, res0, out0, zero columns (k=39 inserted zero col; 4561.. pad)
  float xv = 0.f;
  if (lane < NPG) {
    xv = x[(size_t)base + lane];
    f_row[lane] = f2b(xv);
  }
  if (lane == 0) f_row[39] = 0;
  if (lane < KP - 4561) f_row[4561 + lane] = 0;
  float mx = (lane < NPG) ? xv : -3.4e38f;
#pragma unroll
  for (int st = 1; st < 64; st <<= 1) { float t = __shfl_xor(mx, st); mx = fmaxf(mx, t); }
  if (lane == 0) f_row[4447] = f2b(mx);            // out0 = max over raw x
  if (lane < NPG) cnt[lane] = 1;                   // self loop pre-count
  wsync();

  // degree count (edges stashed in registers for the scatter pass)
  int es[5], ed[5];
#pragma unroll
  for (int it = 0; it < 5; ++it) {
    int e = lane + 64 * it;
    if (e < EPG) {
      int s = srcg[e] - base, d = dstg[e] - base;
      s = min(max(s, 0), NPG - 1);
      d = min(max(d, 0), NPG - 1);
      es[it] = s; ed[it] = d;
      atomicAdd(&cnt[d], 1);
    } else { es[it] = -1; ed[it] = 0; }
  }
  wsync();

  // exclusive prefix sum via wave scan (uniform control flow)
  int c = (lane < NPG) ? cnt[lane] : 0;
  int v = c;
#pragma unroll
  for (int off = 1; off < 64; off <<= 1) { int t = __shfl_up(v, off); if (lane >= off) v += t; }
  int excl = v - c;
  if (lane < NPG) csr_ptr[lane] = (unsigned short)excl;
  if (lane == NPG - 1) csr_ptr[NPG] = (unsigned short)EDG;
  wsync();
  if (lane < NPG) cnt[lane] = excl;                // running positions
  wsync();

  // scatter: self loops + edges
  if (lane < NPG) { int p = atomicAdd(&cnt[lane], 1); csr_src[p] = (unsigned char)lane; }
#pragma unroll
  for (int it = 0; it < 5; ++it) {
    if (es[it] >= 0) {
      int p = atomicAdd(&cnt[ed[it]], 1);
      p = min(p, EDG - 1);
      csr_src[p] = (unsigned char)es[it];
    }
  }
  wsync();

  const unsigned short* Wb2 = Wb;                  // [80][32]
  const unsigned short* Wb3 = Wb + 2560;           // [48][64]
  const unsigned short* Wb4 = Wb + 5632;           // [16][32]

  //      Fi  Fo KPAD KT1 NT HALV DT SCOL DCOL INSRC OUTDST GSYNC  in_off res  out
  layerM< 1,  8,  0,  0,  1,  1,  0,  0,  0,   0,    1,  false>(xv, nullptr, W1, as1, ad1, b1, f_row, 0,    40,   4448, lane);
  layerM< 8, 64, 32,  1,  4,  2,  4,  0,  1,   1,    0,  false>(0.f, Wb2, nullptr, nullptr, nullptr, b2, f_row, 0,    352,  4456, lane);
  layerM<64, 32, 64,  2,  2,  1,  2,  0,  1,   2,    1,  true >(0.f, Wb3, nullptr, nullptr, nullptr, b3, f_row, 352,  2848, 4520, lane);
  layerM<32,  9, 32,  1,  1,  1,  0, 10, 11,   1,    0,  false>(0.f, Wb4, nullptr, nullptr, nullptr, b4, f_row, 0,    4096, 4552, lane);
}

// ============ prep: W fragments (B^T layout) + attn-dot columns ============
__global__ __launch_bounds__(256) void prep_wb(
    const float* __restrict__ W2, const float* __restrict__ as2, const float* __restrict__ ad2,
    const float* __restrict__ W3, const float* __restrict__ as3, const float* __restrict__ ad3,
    const float* __restrict__ W4, const float* __restrict__ as4, const float* __restrict__ ad4,
    const float* __restrict__ w3mlp,
    unsigned short* __restrict__ Wb) {
  const int tid = threadIdx.x;
  for (int i = tid; i < 80 * 32; i += 256) {
    int o = i >> 5, k = i & 31; float v = 0.f;
    if (k < 8) {
      if (o < 64) v = W2[k * 64 + o];
      else if (o == 64 || o == 68) { float s = 0; for (int j = 0; j < 64; ++j) s += W2[k * 64 + j] * as2[j];
        float hi = b2f(f2b(s)); v = (o == 64) ? hi : (s - hi); }
      else if (o == 65 || o == 69) { float s = 0; for (int j = 0; j < 64; ++j) s += W2[k * 64 + j] * ad2[j];
        float hi = b2f(f2b(s)); v = (o == 65) ? hi : (s - hi); }
    }
    Wb[i] = f2b(v);
  }
  for (int i = tid; i < 48 * 64; i += 256) {
    int o = i >> 6, k = i & 63; float v = 0.f;
    if (o < 32) v = W3[k * 32 + o];
    else if (o == 32 || o == 36) { float s = 0; for (int j = 0; j < 32; ++j) s += W3[k * 32 + j] * as3[j];
      float hi = b2f(f2b(s)); v = (o == 32) ? hi : (s - hi); }
    else if (o == 33 || o == 37) { float s = 0; for (int j = 0; j < 32; ++j) s += W3[k * 32 + j] * ad3[j];
      float hi = b2f(f2b(s)); v = (o == 33) ? hi : (s - hi); }
    Wb[2560 + i] = f2b(v);
  }
  for (int i = tid; i < 16 * 32; i += 256) {
    int o = i >> 5, k = i & 31; float v = 0.f;
    if (o < 9) v = W4[k * 9 + o];
    else if (o == 10 || o == 14) { float s = 0; for (int j = 0; j < 9; ++j) s += W4[k * 9 + j] * as4[j];
      float hi = b2f(f2b(s)); v = (o == 10) ? hi : (s - hi); }
    else if (o == 11 || o == 15) { float s = 0; for (int j = 0; j < 9; ++j) s += W4[k * 9 + j] * ad4[j];
      float hi = b2f(f2b(s)); v = (o == 11) ? hi : (s - hi); }
    Wb[5632 + i] = f2b(v);
  }
  // w3 in B-fragment layout [16 cols][128 k] (cols 9..15 zero) at Wb+6144
  for (int i = tid; i < 16 * 128; i += 256) {
    int c = i >> 7, k = i & 127;
    Wb[6144 + i] = f2b((c < 9) ? w3mlp[k * 9 + c] : 0.f);
  }
}

// ================= weight transpose + bf16 cast (per launch) =================
template<bool PERM>
__global__ __launch_bounds__(256) void tcast(const float* __restrict__ in,
                                             unsigned short* __restrict__ out,
                                             int K, int NN, int Kpad) {
  __shared__ float tile[64 * 65];
  const int k0 = blockIdx.x * 64, n0 = blockIdx.y * 64;
  const int tid = threadIdx.x;
#pragma unroll
  for (int i = 0; i < 16; ++i) {
    int idx = i * 256 + tid;
    int r = idx >> 6, c = idx & 63;
    int k = k0 + r;
    int ko;
    if constexpr (PERM) {
      ko = (k < 39) ? k : ((k == 39 || k > FDIM) ? -1 : k - 1);
    } else {
      ko = (k < K) ? k : -1;
    }
    tile[r * 65 + c] = (ko >= 0) ? in[(size_t)ko * NN + n0 + c] : 0.f;
  }
  __syncthreads();
#pragma unroll
  for (int i = 0; i < 16; ++i) {
    int idx = i * 256 + tid;
    int r = idx >> 6, c = idx & 63;    // r: n-offset, c: k-offset
    out[(size_t)(n0 + r) * Kpad + k0 + c] = f2b(tile[c * 65 + r]);
  }
}

// ====== bf16 MFMA GEMM (128x64 tile, BK=64, swizzled, XCD-clustered, 2-phase dbuf) ======
// 1024 blocks -> 4/CU-capable; LDS 48KB -> 3 blocks/CU (12 waves/CU vs 8 at
// the 128x128 tile): more independent K-pipelines hide the staging latency.
// 6 global_load_lds per wave per tile (4 A + 2 B) -> steady-state vmcnt(6).
template<bool OUT_BF16>
__global__ __launch_bounds__(256) void mfma_gemm(const unsigned short* __restrict__ A,
    const unsigned short* __restrict__ Bt, unsigned short* __restrict__ Cb,
    float* __restrict__ Cf, const float* __restrict__ bias, int K, int N, int gridN) {
  __shared__ alignas(16) unsigned short As[2][128 * 64];
  __shared__ alignas(16) unsigned short Bs[2][64 * 64];
  const int tid = threadIdx.x;
  const int lane = tid & 63;
  const int wave = tid >> 6;
  const int wy = wave >> 1, wx = wave & 1;

  const int wg = blockIdx.x;
  const int xcd = wg & 7, idx = wg >> 3;
  const int mpr = (int)(gridDim.x >> 3) / gridN;   // m-rows per XCD
  const int m_local = idx / gridN;
  const int n = idx - m_local * gridN;
  const int m0 = (xcd * mpr + m_local) * 128;
  const int n0 = n * 64;

  f32x4 acc[4][2];
  const f32x4 z = {0.f, 0.f, 0.f, 0.f};
#pragma unroll
  for (int i = 0; i < 4; ++i)
#pragma unroll
    for (int j = 0; j < 2; ++j) acc[i][j] = z;

  const int srow = lane >> 3;                  // row within 8-row store group
  const int sch  = (lane & 7) ^ srow;          // swizzled source 16B chunk
  const int q    = lane >> 4;                  // k sub-chunk 0..3
  const int rm   = lane & 15;

  // 6 global_load_lds per wave per tile (4 A-steps + 2 B-steps)
#define STAGE(buf, kk0)                                                              \
  {                                                                                  \
    _Pragma("unroll")                                                                \
    for (int t = 0; t < 4; ++t) {                                                    \
      int r0 = wave * 32 + t * 8;                                                    \
      const unsigned short* ga = A + (size_t)(m0 + r0 + srow) * K + (kk0) + sch * 8; \
      __builtin_amdgcn_global_load_lds(                                              \
          (const __attribute__((address_space(1))) unsigned int*)(const void*)ga,    \
          (__attribute__((address_space(3))) unsigned int*)(void*)&As[buf][r0 * 64], \
          16, 0, 0);                                                                 \
    }                                                                                \
    _Pragma("unroll")                                                                \
    for (int t = 0; t < 2; ++t) {                                                    \
      int r0 = wave * 16 + t * 8;                                                    \
      const unsigned short* gb = Bt + (size_t)(n0 + r0 + srow) * K + (kk0) + sch * 8;\
      __builtin_amdgcn_global_load_lds(                                              \
          (const __attribute__((address_space(1))) unsigned int*)(const void*)gb,    \
          (__attribute__((address_space(3))) unsigned int*)(void*)&Bs[buf][r0 * 64], \
          16, 0, 0);                                                                 \
    }                                                                                \
  }

  STAGE(0, 0);
  int cur = 0;
  for (int k0 = 0; k0 < K; k0 += 64) {
    if (k0 + 64 < K) {
      STAGE(cur ^ 1, k0 + 64);                 // prefetch next tile
      asm volatile("s_waitcnt vmcnt(6)" ::: "memory");   // current tile landed
    } else {
      asm volatile("s_waitcnt vmcnt(0)" ::: "memory");
    }
    __builtin_amdgcn_s_barrier();              // all waves' current loads done
#pragma unroll
    for (int kk = 0; kk < 2; ++kk) {
      bf16x8 af[4], bfr[2];
#pragma unroll
      for (int i = 0; i < 4; ++i) {
        int ra = wy * 64 + i * 16 + rm;
        af[i] = *(const bf16x8*)&As[cur][ra * 64 + (((kk * 4 + q) ^ (ra & 7)) << 3)];
      }
#pragma unroll
      for (int j = 0; j < 2; ++j) {
        int rb = wx * 32 + j * 16 + rm;
        bfr[j] = *(const bf16x8*)&Bs[cur][rb * 64 + (((kk * 4 + q) ^ (rb & 7)) << 3)];
      }
#pragma unroll
      for (int i = 0; i < 4; ++i)
#pragma unroll
        for (int j = 0; j < 2; ++j)
          acc[i][j] = __builtin_amdgcn_mfma_f32_16x16x32_bf16(af[i], bfr[j], acc[i][j], 0, 0, 0);
    }
    __builtin_amdgcn_s_barrier();              // reads done before next overwrite
    cur ^= 1;
  }
#undef STAGE

  const int q4 = (lane >> 4) * 4;
#pragma unroll
  for (int i = 0; i < 4; ++i) {
#pragma unroll
    for (int j = 0; j < 2; ++j) {
      int row = m0 + wy * 64 + i * 16 + q4;
      int col = n0 + wx * 32 + j * 16 + rm;
      float bv = bias[col];
#pragma unroll
      for (int v = 0; v < 4; ++v) {
        float val = fmaxf(acc[i][j][v] + bv, 0.f);
        if constexpr (OUT_BF16) Cb[(size_t)(row + v) * N + col] = f2b(val);
        else                    Cf[(size_t)(row + v) * N + col] = val;
      }
    }
  }
}

// ====== fused gemm2 + mlp3: out = relu(g1@w2t + b2) @ w3 + b3 ======
// 2-phase K-loop (K=1024, N=128, 64 blocks). Epilogue stages the 128x128 g2
// tile (bf16, swizzled) into the dead As LDS, then a 4-deep MFMA chain
// against w3b [16][128] produces the final [128][9] f32 rows.
__global__ __launch_bounds__(256) void gemm2_fused(const unsigned short* __restrict__ A,
    const unsigned short* __restrict__ Bt, const unsigned short* __restrict__ w3b,
    const float* __restrict__ bias2, const float* __restrict__ b3,
    float* __restrict__ out) {
  __shared__ alignas(16) unsigned short As[2][128 * 64];
  __shared__ alignas(16) unsigned short Bs[2][128 * 64];
  const int tid = threadIdx.x;
  const int lane = tid & 63;
  const int wave = tid >> 6;
  const int wy = wave >> 1, wx = wave & 1;
  const int m0 = blockIdx.x * 128;
  const int K = 1024;

  f32x4 acc[4][4];
  const f32x4 z = {0.f, 0.f, 0.f, 0.f};
#pragma unroll
  for (int i = 0; i < 4; ++i)
#pragma unroll
    for (int j = 0; j < 4; ++j) acc[i][j] = z;

  const int srow = lane >> 3;
  const int sch  = (lane & 7) ^ srow;
  const int q    = lane >> 4;
  const int rm   = lane & 15;

#define STAGE2(buf, kk0)                                                             \
  {                                                                                  \
    _Pragma("unroll")                                                                \
    for (int t = 0; t < 4; ++t) {                                                    \
      int r0 = wave * 32 + t * 8;                                                    \
      const unsigned short* ga = A  + (size_t)(m0 + r0 + srow) * K + (kk0) + sch * 8;\
      const unsigned short* gb = Bt + (size_t)(r0 + srow) * K + (kk0) + sch * 8;     \
      __builtin_amdgcn_global_load_lds(                                              \
          (const __attribute__((address_space(1))) unsigned int*)(const void*)ga,    \
          (__attribute__((address_space(3))) unsigned int*)(void*)&As[buf][r0 * 64], \
          16, 0, 0);                                                                 \
      __builtin_amdgcn_global_load_lds(                                              \
          (const __attribute__((address_space(1))) unsigned int*)(const void*)gb,    \
          (__attribute__((address_space(3))) unsigned int*)(void*)&Bs[buf][r0 * 64], \
          16, 0, 0);                                                                 \
    }                                                                                \
  }

  STAGE2(0, 0);
  int cur = 0;
  for (int k0 = 0; k0 < K; k0 += 64) {
    if (k0 + 64 < K) {
      STAGE2(cur ^ 1, k0 + 64);
      asm volatile("s_waitcnt vmcnt(8)" ::: "memory");
    } else {
      asm volatile("s_waitcnt vmcnt(0)" ::: "memory");
    }
    __builtin_amdgcn_s_barrier();
#pragma unroll
    for (int kk = 0; kk < 2; ++kk) {
      bf16x8 af[4], bfr[4];
#pragma unroll
      for (int i = 0; i < 4; ++i) {
        int ra = wy * 64 + i * 16 + rm;
        int rb = wx * 64 + i * 16 + rm;
        af[i]  = *(const bf16x8*)&As[cur][ra * 64 + (((kk * 4 + q) ^ (ra & 7)) << 3)];
        bfr[i] = *(const bf16x8*)&Bs[cur][rb * 64 + (((kk * 4 + q) ^ (rb & 7)) << 3)];
      }
#pragma unroll
      for (int i = 0; i < 4; ++i)
#pragma unroll
        for (int j = 0; j < 4; ++j)
          acc[i][j] = __builtin_amdgcn_mfma_f32_16x16x32_bf16(af[i], bfr[j], acc[i][j], 0, 0, 0);
    }
    __builtin_amdgcn_s_barrier();
    cur ^= 1;
  }
#undef STAGE2

  // ---- stage g2 = relu(acc + b2) into As (bf16 [128][128], oct-swizzled) ----
  unsigned short* gs = &As[0][0];                // 32 KB, dead after K loop
  const int q4 = q * 4;
#pragma unroll
  for (int i = 0; i < 4; ++i) {
#pragma unroll
    for (int j = 0; j < 4; ++j) {
      int cl = wx * 64 + j * 16 + rm;            // local col 0..127
      float bv = bias2[cl];
#pragma unroll
      for (int v = 0; v < 4; ++v) {
        int r = wy * 64 + i * 16 + q4 + v;       // local row 0..127
        float val = fmaxf(acc[i][j][v] + bv, 0.f);
        gs[r * 128 + ((((cl >> 3) ^ (r & 7)) << 3) | (cl & 7))] = f2b(val);
      }
    }
  }
  __syncthreads();

  // ---- mini-GEMM: out_tile[128][9] = g2 @ w3 + b3 (each wave: 2 m-tiles) ----
  f32x4 a2[2];
#pragma unroll
  for (int i = 0; i < 2; ++i) a2[i] = z;
#pragma unroll
  for (int kt = 0; kt < 4; ++kt) {
    bf16x8 bW3 = *(const bf16x8*)&w3b[rm * 128 + kt * 32 + q * 8];
#pragma unroll
    for (int i = 0; i < 2; ++i) {
      int row = (wave * 2 + i) * 16 + rm;
      bf16x8 aG = *(const bf16x8*)&gs[row * 128 + (((kt * 4 + q) ^ (row & 7)) << 3)];
      a2[i] = __builtin_amdgcn_mfma_f32_16x16x32_bf16(aG, bW3, a2[i], 0, 0, 0);
    }
  }
#pragma unroll
  for (int i = 0; i < 2; ++i) {
    if (rm < 9) {
      float bv = b3[rm];
#pragma unroll
      for (int v = 0; v < 4; ++v) {
        int row = m0 + (wave * 2 + i) * 16 + q4 + v;
        out[(size_t)row * 9 + rm] = a2[i][v] + bv;
      }
    }
  }
}

// =========================== launch ===========================
extern "C" void kernel_launch(void* const* d_in, const int* in_sizes, int n_in,
                              void* d_out, int out_size, void* d_ws, size_t ws_size,
                              hipStream_t stream) {
  const float* x   = (const float*)d_in[0];
  const int*   ei  = (const int*)d_in[1];
  const float* W1  = (const float*)d_in[3];
  const float* as1 = (const float*)d_in[4];
  const float* ad1 = (const float*)d_in[5];
  const float* b1  = (const float*)d_in[6];
  const float* W2  = (const float*)d_in[7];
  const float* as2 = (const float*)d_in[8];
  const float* ad2 = (const float*)d_in[9];
  const float* b2  = (const float*)d_in[10];
  const float* W3  = (const float*)d_in[11];
  const float* as3 = (const float*)d_in[12];
  const float* ad3 = (const float*)d_in[13];
  const float* b3  = (const float*)d_in[14];
  const float* W4  = (const float*)d_in[15];
  const float* as4 = (const float*)d_in[16];
  const float* ad4 = (const float*)d_in[17];
  const float* b4  = (const float*)d_in[18];
  const float* lw1 = (const float*)d_in[19];
  const float* lb1 = (const float*)d_in[20];
  const float* lw2 = (const float*)d_in[21];
  const float* lb2 = (const float*)d_in[22];
  const float* lw3 = (const float*)d_in[23];
  const float* lb3 = (const float*)d_in[24];
  float* out = (float*)d_out;

  // workspace carve-up (bf16 stored as u16)
  unsigned short* f   = (unsigned short*)d_ws;            // [8192][4608] bf16
  unsigned short* w1t = f   + (size_t)NGRAPH * KP;        // [1024][4608] bf16
  unsigned short* w2t = w1t + (size_t)1024 * KP;          // [128][1024]  bf16
  unsigned short* g1  = w2t + (size_t)128 * 1024;         // [8192][1024] bf16
  // Wb lives in the old-g2 region (AFTER g1) so it survives gemm1's g1 write:
  // gemm2_fused reads w3b from it. ~16 KB of the 4 MB region.
  unsigned short* Wb  = g1 + (size_t)NGRAPH * 1024;

  prep_wb<<<1, 256, 0, stream>>>(W2, as2, ad2, W3, as3, ad3, W4, as4, ad4, lw3, Wb);
  tcast<true ><<<dim3(KP / 64, 1024 / 64), 256, 0, stream>>>(lw1, w1t, FDIM, 1024, KP);
  tcast<false><<<dim3(1024 / 64, 128 / 64), 256, 0, stream>>>(lw2, w2t, 1024, 128, 1024);

  gat_fused<<<NGRAPH, 64, 0, stream>>>(x, ei, W1, as1, ad1,
      b1, b2, b3, b4, Wb, f);

  mfma_gemm<true ><<<1024, 256, 0, stream>>>(
      f, w1t, g1, nullptr, lb1, KP, 1024, 16);

  gemm2_fused<<<NGRAPH / 128, 256, 0, stream>>>(
      g1, w2t, Wb + 6144, lb2, lb3, out);
}

// Round 19
// 207.702 us; speedup vs baseline: 1.1340x; 1.1340x over previous
//
#include <hip/hip_runtime.h>

// Problem constants
#define NPG   39
#define NGRAPH 8192
#define EPG   312           // input edges per graph
#define EDG   351           // + 39 self loops
#define E0    2555904       // total input edges (8192*312)
#define FDIM  4560
#define KP    4608          // padded K for bf16 GEMM (multiple of 128)

typedef __bf16 bf16x8 __attribute__((ext_vector_type(8)));
typedef float  f32x4  __attribute__((ext_vector_type(4)));

__device__ __forceinline__ unsigned short f2b(float f) {
  unsigned int u = __float_as_uint(f);
  u += 0x7fffu + ((u >> 16) & 1u);            // RNE to bf16
  return (unsigned short)(u >> 16);
}
__device__ __forceinline__ unsigned int pk2(float lo, float hi) {
  return (unsigned int)f2b(lo) | ((unsigned int)f2b(hi) << 16);
}
__device__ __forceinline__ float b2f(unsigned short u) {
  return __uint_as_float((unsigned int)u << 16);
}
// wave-level "barrier": single wave per workgroup -> LDS drain + compiler fence
__device__ __forceinline__ void wsync() {
  asm volatile("s_waitcnt lgkmcnt(0)" ::: "memory");
}
// drain global stores (f_row RAW across layers, same CU)
__device__ __forceinline__ void gsync() {
  asm volatile("s_waitcnt vmcnt(0) lgkmcnt(0)" ::: "memory");
}

// =================== per-graph LDS (one wave per graph) ===================
__shared__ alignas(16) unsigned short Htb[32 * 64];      // 4096 B
__shared__ alignas(16) unsigned short alf16[40 * 64];    // 5120 B
__shared__ float sn[40];                                 // src attn scalars (alias: cnt)
__shared__ float dn[48];                                 // d-dot, then 1/den (pad 48)
__shared__ unsigned char csr_src[EDG + 1];
__shared__ unsigned short csr_ptr[NPG + 1];

// ======================= fused GAT layer (per wave) =======================
// INSRC: 0 = x register (L1), 1 = alf16 (prev layer staged), 2 = f_row.
// OUTDST: 0 = Htb staging (L2 halves, L4), 1 = alf16 staging (-> next layer).
template<int Fi, int Fo, int KPAD, int KT1, int NT, int HALVES,
         int DT, int SCOL, int DCOL, int INSRC, int OUTDST, bool GSYNC>
__device__ __forceinline__ void layerM(float x0,
                                       const unsigned short* __restrict__ Wb,
                                       const float* __restrict__ W1,
                                       const float* __restrict__ as1,
                                       const float* __restrict__ ad1,
                                       const float* __restrict__ bias,
                                       unsigned short* __restrict__ f_row,
                                       int in_off, int res_off, int out_off,
                                       int lane) {
  constexpr int NTH = NT / HALVES;
  constexpr int RMASK = (Fi >= 16) ? (Fi / 8 - 1) : 0;  // alf16 input swizzle
  constexpr int WMASK = (Fo >= 16) ? (Fo / 8 - 1) : 0;  // alf16 output swizzle
  constexpr int VW  = (HALVES == 2) ? 32 : Fo;          // Htb staging row width
  constexpr bool SWZST = (VW == 32);
  const int r15 = lane & 15, g = lane >> 4;
  const f32x4 z = {0.f, 0.f, 0.f, 0.f};
  const uint4 z4 = {0u, 0u, 0u, 0u};

  f32x4 c1[3][NT];                               // feature tiles (Fi>1)

  // ---------------- P1: c1 tiles + attention dot columns ----------------
  if constexpr (Fi == 1) {
    float was = 0.f, wad = 0.f;
#pragma unroll
    for (int o = 0; o < 8; ++o) { float w = W1[o]; was += w * as1[o]; wad += w * ad1[o]; }
    if (lane < NPG) {
      sn[lane] = x0 * was; dn[lane] = x0 * wad;
#pragma unroll
      for (int o = 0; o < 8; ++o) {              // Ht written directly
        int idx = o * 64 + ((((lane >> 3) ^ (o & 7)) << 3)) + (lane & 7);
        Htb[idx] = f2b(x0 * W1[o]);
      }
    }
  } else {
    if constexpr (GSYNC) gsync();                // L2's f flush must land
    f32x4 cd[3];
#pragma unroll
    for (int mt = 0; mt < 3; ++mt) cd[mt] = z;
#pragma unroll
    for (int mt = 0; mt < 3; ++mt)
#pragma unroll
      for (int nt = 0; nt < NT; ++nt) c1[mt][nt] = z;
    __builtin_amdgcn_s_setprio(1);
#pragma unroll
    for (int kt = 0; kt < KT1; ++kt) {
      bf16x8 aF[3];
#pragma unroll
      for (int mt = 0; mt < 3; ++mt) {
        int row = 16 * mt + r15;
        if constexpr (INSRC == 2) {
          row = (row > 39) ? 39 : row;           // never read uninit f bytes
          aF[mt] = *(const bf16x8*)&f_row[in_off + row * Fi + kt * 32 + g * 8];
        } else {
          aF[mt] = *(const bf16x8*)&alf16[row * Fi + (((kt * 4 + g) ^ (row & RMASK)) << 3)];
        }
      }
      if constexpr (DT >= NT) {                  // separate dot tile
        bf16x8 bD = *(const bf16x8*)&Wb[(16 * DT + r15) * KPAD + kt * 32 + g * 8];
#pragma unroll
        for (int mt = 0; mt < 3; ++mt)
          cd[mt] = __builtin_amdgcn_mfma_f32_16x16x32_bf16(aF[mt], bD, cd[mt], 0, 0, 0);
      }
#pragma unroll
      for (int nt = 0; nt < NT; ++nt) {
        bf16x8 bW = *(const bf16x8*)&Wb[(16 * nt + r15) * KPAD + kt * 32 + g * 8];
#pragma unroll
        for (int mt = 0; mt < 3; ++mt)
          c1[mt][nt] = __builtin_amdgcn_mfma_f32_16x16x32_bf16(aF[mt], bW, c1[mt][nt], 0, 0, 0);
      }
    }
    __builtin_amdgcn_s_setprio(0);
#pragma unroll
    for (int mt = 0; mt < 3; ++mt)
#pragma unroll
      for (int v = 0; v < 4; ++v) {
        float base = (DT >= NT) ? cd[mt][v] : c1[mt][DT][v];
        float t = base + __shfl_xor(base, 4);    // hi + lo column
        int r = 16 * mt + g * 4 + v;
        if (r15 == SCOL && r < NPG) sn[r] = t;
        if (r15 == DCOL && r < NPG) dn[r] = t;
      }
  }
  wsync();                                       // input consumed; sn/dn visible

  // ---- wave-global softmax shift (softmax is shift-invariant; lrelu is
  //      monotone so mg = lrelu(max sn + max dn) >= every e) ----
  float svm = (lane < NPG) ? sn[lane] : -3.4e38f;
  float dvm = (lane < NPG) ? dn[lane] : -3.4e38f;
#pragma unroll
  for (int st = 1; st < 64; st <<= 1) {
    svm = fmaxf(svm, __shfl_xor(svm, st));
    dvm = fmaxf(dvm, __shfl_xor(dvm, st));
  }
  float mg = svm + dvm;
  mg = (mg >= 0.f) ? mg : 0.2f * mg;

  // ---- zero alpha (deferred: input in alf16 already consumed into c1) ----
#pragma unroll
  for (int i = 0; i < 5; ++i) *(uint4*)&alf16[lane * 8 + i * 512] = z4;
  wsync();

  // ---- P3: per-dst softmax (single pass; global shift mg) ----
  if (lane < NPG) {
    int rs = csr_ptr[lane], re = csr_ptr[lane + 1];
    float dv = dn[lane];
    float den = 0.f;
    for (int k = rs; k < re; ++k) {
      int s = csr_src[k];
      float e = sn[s] + dv;
      e = (e >= 0.f) ? e : 0.2f * e;
      float w = __expf(e - mg);
      int idx = lane * 64 + ((((s >> 3) ^ (lane & 7)) << 3)) + (s & 7);
      float cur = b2f(alf16[idx]);               // duplicate edges accumulate
      unsigned short nb = f2b(cur + w);
      alf16[idx] = nb;
      den += b2f(nb) - cur;                      // den == sum of stored values
    }
    dn[lane] = 1.f / (den + 1e-16f);
  }
  wsync();

  // ---------------- P4: Out = alpha @ H via MFMA, per half ----------------
  float invr[3][4];
#pragma unroll
  for (int mt = 0; mt < 3; ++mt)
#pragma unroll
    for (int v = 0; v < 4; ++v) invr[mt][v] = dn[16 * mt + g * 4 + v];

  float pool_[NT];
#pragma unroll
  for (int s = 0; s < NT; ++s) pool_[s] = 0.f;

#pragma unroll
  for (int h = 0; h < HALVES; ++h) {
    const int colbase = (HALVES == 2) ? 32 * h : 0;
    if constexpr (Fi > 1) {                      // Ht from c1 registers
#pragma unroll
      for (int tl = 0; tl < NTH; ++tl) {
        int p = r15 + 16 * tl;
#pragma unroll
        for (int mt = 0; mt < 3; ++mt) {
          uint2 w;
          w.x = pk2(c1[mt][h * NTH + tl][0], c1[mt][h * NTH + tl][1]);
          w.y = pk2(c1[mt][h * NTH + tl][2], c1[mt][h * NTH + tl][3]);
          int idx = p * 64 + (((2 * mt + (g >> 1)) ^ (p & 7)) << 3) + (g & 1) * 4;
          *(uint2*)&Htb[idx] = w;
        }
      }
    }
    wsync();
    // alpha @ Ht
    f32x4 c2[3][NTH];
#pragma unroll
    for (int mt = 0; mt < 3; ++mt)
#pragma unroll
      for (int tl = 0; tl < NTH; ++tl) c2[mt][tl] = z;
    __builtin_amdgcn_s_setprio(1);
#pragma unroll
    for (int kt = 0; kt < 2; ++kt) {
      bf16x8 aA[3];
#pragma unroll
      for (int mt = 0; mt < 3; ++mt) {
        int row = 16 * mt + r15;
        aA[mt] = *(const bf16x8*)&alf16[row * 64 + ((((4 * kt + g) ^ (row & 7))) << 3)];
      }
#pragma unroll
      for (int tl = 0; tl < NTH; ++tl) {
        int p = r15 + 16 * tl;
        bf16x8 bH = *(const bf16x8*)&Htb[p * 64 + ((((4 * kt + g) ^ (p & 7))) << 3)];
#pragma unroll
        for (int mt = 0; mt < 3; ++mt)
          c2[mt][tl] = __builtin_amdgcn_mfma_f32_16x16x32_bf16(aA[mt], bH, c2[mt][tl], 0, 0, 0);
      }
    }
    __builtin_amdgcn_s_setprio(0);
    // epilogue: 1/den, bias, relu, stage (alpha/Ht dead post-c2), pool
#pragma unroll
    for (int tl = 0; tl < NTH; ++tl) {
      int c = r15 + 16 * (h * NTH + tl);
      float bv = (c < Fo) ? bias[c] : 0.f;
#pragma unroll
      for (int mt = 0; mt < 3; ++mt)
#pragma unroll
        for (int v = 0; v < 4; ++v) {
          int r = 16 * mt + g * 4 + v;
          float val = fmaxf(c2[mt][tl][v] * invr[mt][v] + bv, 0.f);
          if (r < NPG && c < Fo) {
            if constexpr (OUTDST == 1) {
              alf16[r * Fo + ((((c >> 3) ^ (r & WMASK)) << 3) | (c & 7))] = f2b(val);
            } else {
              int sc = c - colbase;
              int so = SWZST ? ((sc >> 3) ^ ((r >> 2) & 3)) : (sc >> 3);
              Htb[r * VW + (so << 3) + (sc & 7)] = f2b(val);
            }
            pool_[h * NTH + tl] = fmaxf(pool_[h * NTH + tl], val);
          }
        }
    }
    wsync();                                     // staging visible cross-lane

    // ---- residual flush: staging -> f_row, full 16B lines ----
    if constexpr (OUTDST == 1) {
      if constexpr (Fo == 8) {
        if (lane < NPG)
          *(uint4*)&f_row[res_off + lane * 8] = *(const uint4*)&alf16[lane * 8];
      } else {                                   // Fo == 32
        for (int j = lane; j < NPG * 4; j += 64) {
          int r = j >> 2, o = j & 3;
          *(uint4*)&f_row[res_off + r * 32 + 8 * o] =
              *(const uint4*)&alf16[r * 32 + ((o ^ (r & 3)) << 3)];
        }
      }
    } else if constexpr (Fo == 9) {
      for (int j = lane; j < 43; j += 64)
        *(uint4*)&f_row[res_off + j * 8] = *(const uint4*)&Htb[j * 8];
      if (lane < 7) f_row[res_off + 344 + lane] = Htb[344 + lane];
    } else {                                     // L2 halves (VW=32)
      for (int j = lane; j < NPG * 4; j += 64) {
        int r = j >> 2, o = j & 3;
        int so = o ^ ((r >> 2) & 3);
        *(uint4*)&f_row[res_off + r * Fo + colbase + 8 * o] =
            *(const uint4*)&Htb[r * VW + 8 * so];
      }
    }
    wsync();                                     // before next half's Ht writes
  }

  // ---- P5: per-graph max pool (cross-lane over row groups) ----
#pragma unroll
  for (int s = 0; s < NT; ++s) {
    float pv = pool_[s];
    pv = fmaxf(pv, __shfl_xor(pv, 16));
    pv = fmaxf(pv, __shfl_xor(pv, 32));
    int c = r15 + 16 * s;
    if (g == 0 && c < Fo) f_row[out_off + c] = f2b(pv);
  }
}

// =========================== fused GAT kernel ===========================
__global__ __launch_bounds__(64, 4) void gat_fused(
    const float* __restrict__ x, const int* __restrict__ ei,
    const float* __restrict__ W1, const float* __restrict__ as1, const float* __restrict__ ad1,
    const float* __restrict__ b1, const float* __restrict__ b2,
    const float* __restrict__ b3, const float* __restrict__ b4,
    const unsigned short* __restrict__ Wb,
    unsigned short* __restrict__ f) {
  const int b = blockIdx.x;
  const int lane = threadIdx.x;                    // one wave per graph
  const int base = b * NPG;
  const int* srcg = ei + (size_t)b * EPG;
  const int* dstg = ei + E0 + (size_t)b * EPG;
  unsigned short* f_row = f + (size_t)b * KP;
  int* cnt = (int*)sn;                             // alias: sn unused until layers
  const uint4 z4 = {0u, 0u, 0u, 0u};

  // zero Ht once (finite content guarantee for never-written node-cols 48-63)
#pragma unroll
  for (int i = 0; i < 4; ++i) *(uint4*)&Htb[lane * 8 + i * 512] = z4;

  // x load, res0, out0, zero columns (k=39 inserted zero col; 4561.. pad)
  float xv = 0.f;
  if (lane < NPG) {
    xv = x[(size_t)base + lane];
    f_row[lane] = f2b(xv);
  }
  if (lane == 0) f_row[39] = 0;
  if (lane < KP - 4561) f_row[4561 + lane] = 0;
  float mx = (lane < NPG) ? xv : -3.4e38f;
#pragma unroll
  for (int st = 1; st < 64; st <<= 1) { float t = __shfl_xor(mx, st); mx = fmaxf(mx, t); }
  if (lane == 0) f_row[4447] = f2b(mx);            // out0 = max over raw x
  if (lane < NPG) cnt[lane] = 1;                   // self loop pre-count
  wsync();

  // degree count (edges stashed in registers for the scatter pass)
  int es[5], ed[5];
#pragma unroll
  for (int it = 0; it < 5; ++it) {
    int e = lane + 64 * it;
    if (e < EPG) {
      int s = srcg[e] - base, d = dstg[e] - base;
      s = min(max(s, 0), NPG - 1);
      d = min(max(d, 0), NPG - 1);
      es[it] = s; ed[it] = d;
      atomicAdd(&cnt[d], 1);
    } else { es[it] = -1; ed[it] = 0; }
  }
  wsync();

  // exclusive prefix sum via wave scan (uniform control flow)
  int c = (lane < NPG) ? cnt[lane] : 0;
  int v = c;
#pragma unroll
  for (int off = 1; off < 64; off <<= 1) { int t = __shfl_up(v, off); if (lane >= off) v += t; }
  int excl = v - c;
  if (lane < NPG) csr_ptr[lane] = (unsigned short)excl;
  if (lane == NPG - 1) csr_ptr[NPG] = (unsigned short)EDG;
  wsync();
  if (lane < NPG) cnt[lane] = excl;                // running positions
  wsync();

  // scatter: self loops + edges
  if (lane < NPG) { int p = atomicAdd(&cnt[lane], 1); csr_src[p] = (unsigned char)lane; }
#pragma unroll
  for (int it = 0; it < 5; ++it) {
    if (es[it] >= 0) {
      int p = atomicAdd(&cnt[ed[it]], 1);
      p = min(p, EDG - 1);
      csr_src[p] = (unsigned char)es[it];
    }
  }
  wsync();

  const unsigned short* Wb2 = Wb;                  // [80][32]
  const unsigned short* Wb3 = Wb + 2560;           // [48][64]
  const unsigned short* Wb4 = Wb + 5632;           // [16][32]

  //      Fi  Fo KPAD KT1 NT HALV DT SCOL DCOL INSRC OUTDST GSYNC  in_off res  out
  layerM< 1,  8,  0,  0,  1,  1,  0,  0,  0,   0,    1,  false>(xv, nullptr, W1, as1, ad1, b1, f_row, 0,    40,   4448, lane);
  layerM< 8, 64, 32,  1,  4,  2,  4,  0,  1,   1,    0,  false>(0.f, Wb2, nullptr, nullptr, nullptr, b2, f_row, 0,    352,  4456, lane);
  layerM<64, 32, 64,  2,  2,  1,  2,  0,  1,   2,    1,  true >(0.f, Wb3, nullptr, nullptr, nullptr, b3, f_row, 352,  2848, 4520, lane);
  layerM<32,  9, 32,  1,  1,  1,  0, 10, 11,   1,    0,  false>(0.f, Wb4, nullptr, nullptr, nullptr, b4, f_row, 0,    4096, 4552, lane);
}

// ============ prep: W fragments (B^T layout) + attn-dot columns ============
__global__ __launch_bounds__(256) void prep_wb(
    const float* __restrict__ W2, const float* __restrict__ as2, const float* __restrict__ ad2,
    const float* __restrict__ W3, const float* __restrict__ as3, const float* __restrict__ ad3,
    const float* __restrict__ W4, const float* __restrict__ as4, const float* __restrict__ ad4,
    const float* __restrict__ w3mlp,
    unsigned short* __restrict__ Wb) {
  const int tid = threadIdx.x;
  for (int i = tid; i < 80 * 32; i += 256) {
    int o = i >> 5, k = i & 31; float v = 0.f;
    if (k < 8) {
      if (o < 64) v = W2[k * 64 + o];
      else if (o == 64 || o == 68) { float s = 0; for (int j = 0; j < 64; ++j) s += W2[k * 64 + j] * as2[j];
        float hi = b2f(f2b(s)); v = (o == 64) ? hi : (s - hi); }
      else if (o == 65 || o == 69) { float s = 0; for (int j = 0; j < 64; ++j) s += W2[k * 64 + j] * ad2[j];
        float hi = b2f(f2b(s)); v = (o == 65) ? hi : (s - hi); }
    }
    Wb[i] = f2b(v);
  }
  for (int i = tid; i < 48 * 64; i += 256) {
    int o = i >> 6, k = i & 63; float v = 0.f;
    if (o < 32) v = W3[k * 32 + o];
    else if (o == 32 || o == 36) { float s = 0; for (int j = 0; j < 32; ++j) s += W3[k * 32 + j] * as3[j];
      float hi = b2f(f2b(s)); v = (o == 32) ? hi : (s - hi); }
    else if (o == 33 || o == 37) { float s = 0; for (int j = 0; j < 32; ++j) s += W3[k * 32 + j] * ad3[j];
      float hi = b2f(f2b(s)); v = (o == 33) ? hi : (s - hi); }
    Wb[2560 + i] = f2b(v);
  }
  for (int i = tid; i < 16 * 32; i += 256) {
    int o = i >> 5, k = i & 31; float v = 0.f;
    if (o < 9) v = W4[k * 9 + o];
    else if (o == 10 || o == 14) { float s = 0; for (int j = 0; j < 9; ++j) s += W4[k * 9 + j] * as4[j];
      float hi = b2f(f2b(s)); v = (o == 10) ? hi : (s - hi); }
    else if (o == 11 || o == 15) { float s = 0; for (int j = 0; j < 9; ++j) s += W4[k * 9 + j] * ad4[j];
      float hi = b2f(f2b(s)); v = (o == 11) ? hi : (s - hi); }
    Wb[5632 + i] = f2b(v);
  }
  // w3 in B-fragment layout [16 cols][128 k] (cols 9..15 zero) at Wb+6144
  for (int i = tid; i < 16 * 128; i += 256) {
    int c = i >> 7, k = i & 127;
    Wb[6144 + i] = f2b((c < 9) ? w3mlp[k * 9 + c] : 0.f);
  }
}

// ================= weight transpose + bf16 cast (per launch) =================
template<bool PERM>
__global__ __launch_bounds__(256) void tcast(const float* __restrict__ in,
                                             unsigned short* __restrict__ out,
                                             int K, int NN, int Kpad) {
  __shared__ float tile[64 * 65];
  const int k0 = blockIdx.x * 64, n0 = blockIdx.y * 64;
  const int tid = threadIdx.x;
#pragma unroll
  for (int i = 0; i < 16; ++i) {
    int idx = i * 256 + tid;
    int r = idx >> 6, c = idx & 63;
    int k = k0 + r;
    int ko;
    if constexpr (PERM) {
      ko = (k < 39) ? k : ((k == 39 || k > FDIM) ? -1 : k - 1);
    } else {
      ko = (k < K) ? k : -1;
    }
    tile[r * 65 + c] = (ko >= 0) ? in[(size_t)ko * NN + n0 + c] : 0.f;
  }
  __syncthreads();
#pragma unroll
  for (int i = 0; i < 16; ++i) {
    int idx = i * 256 + tid;
    int r = idx >> 6, c = idx & 63;    // r: n-offset, c: k-offset
    out[(size_t)(n0 + r) * Kpad + k0 + c] = f2b(tile[c * 65 + r]);
  }
}

// ====== bf16 MFMA GEMM (256x128 tile, 8 waves, BK=64, swizzled, XCD-clustered,
//        2-phase counted-vmcnt dbuf). Grid 256 = 1 block/CU; LDS 96 KB.
//        Per wave: 32 MFMA per K-tile, 6 staged loads -> vmcnt(6). ======
template<bool OUT_BF16>
__global__ __launch_bounds__(512) void mfma_gemm(const unsigned short* __restrict__ A,
    const unsigned short* __restrict__ Bt, unsigned short* __restrict__ Cb,
    float* __restrict__ Cf, const float* __restrict__ bias, int K, int N, int gridN) {
  __shared__ alignas(16) unsigned short As[2][256 * 64];
  __shared__ alignas(16) unsigned short Bs[2][128 * 64];
  const int tid = threadIdx.x;
  const int lane = tid & 63;
  const int wave = tid >> 6;                   // 0..7
  const int wy = wave >> 1, wx = wave & 1;     // 4x2 wave grid

  const int wg = blockIdx.x;
  const int xcd = wg & 7, idx = wg >> 3;
  const int mpr = (int)(gridDim.x >> 3) / gridN;   // m-rows per XCD
  const int m_local = idx / gridN;
  const int n = idx - m_local * gridN;
  const int m0 = (xcd * mpr + m_local) * 256;
  const int n0 = n * 128;

  f32x4 acc[4][4];
  const f32x4 z = {0.f, 0.f, 0.f, 0.f};
#pragma unroll
  for (int i = 0; i < 4; ++i)
#pragma unroll
    for (int j = 0; j < 4; ++j) acc[i][j] = z;

  const int srow = lane >> 3;                  // row within 8-row store group
  const int sch  = (lane & 7) ^ srow;          // swizzled source 16B chunk
  const int q    = lane >> 4;                  // k sub-chunk 0..3
  const int rm   = lane & 15;

  // 6 global_load_lds per lane per tile (4 A-steps + 2 B-steps, 8 waves)
#define STAGE(buf, kk0)                                                              \
  {                                                                                  \
    _Pragma("unroll")                                                                \
    for (int t = 0; t < 4; ++t) {                                                    \
      int r0 = wave * 32 + t * 8;                                                    \
      const unsigned short* ga = A + (size_t)(m0 + r0 + srow) * K + (kk0) + sch * 8; \
      __builtin_amdgcn_global_load_lds(                                              \
          (const __attribute__((address_space(1))) unsigned int*)(const void*)ga,    \
          (__attribute__((address_space(3))) unsigned int*)(void*)&As[buf][r0 * 64], \
          16, 0, 0);                                                                 \
    }                                                                                \
    _Pragma("unroll")                                                                \
    for (int t = 0; t < 2; ++t) {                                                    \
      int r0 = wave * 16 + t * 8;                                                    \
      const unsigned short* gb = Bt + (size_t)(n0 + r0 + srow) * K + (kk0) + sch * 8;\
      __builtin_amdgcn_global_load_lds(                                              \
          (const __attribute__((address_space(1))) unsigned int*)(const void*)gb,    \
          (__attribute__((address_space(3))) unsigned int*)(void*)&Bs[buf][r0 * 64], \
          16, 0, 0);                                                                 \
    }                                                                                \
  }

  STAGE(0, 0);
  int cur = 0;
  for (int k0 = 0; k0 < K; k0 += 64) {
    if (k0 + 64 < K) {
      STAGE(cur ^ 1, k0 + 64);                 // prefetch next tile
      asm volatile("s_waitcnt vmcnt(6)" ::: "memory");   // current tile landed
    } else {
      asm volatile("s_waitcnt vmcnt(0)" ::: "memory");
    }
    __builtin_amdgcn_s_barrier();              // all waves' current loads done
#pragma unroll
    for (int kk = 0; kk < 2; ++kk) {
      bf16x8 af[4], bfr[4];
#pragma unroll
      for (int i = 0; i < 4; ++i) {
        int ra = wy * 64 + i * 16 + rm;
        af[i] = *(const bf16x8*)&As[cur][ra * 64 + (((kk * 4 + q) ^ (ra & 7)) << 3)];
      }
#pragma unroll
      for (int j = 0; j < 4; ++j) {
        int rb = wx * 64 + j * 16 + rm;
        bfr[j] = *(const bf16x8*)&Bs[cur][rb * 64 + (((kk * 4 + q) ^ (rb & 7)) << 3)];
      }
#pragma unroll
      for (int i = 0; i < 4; ++i)
#pragma unroll
        for (int j = 0; j < 4; ++j)
          acc[i][j] = __builtin_amdgcn_mfma_f32_16x16x32_bf16(af[i], bfr[j], acc[i][j], 0, 0, 0);
    }
    __builtin_amdgcn_s_barrier();              // reads done before next overwrite
    cur ^= 1;
  }
#undef STAGE

  const int q4 = (lane >> 4) * 4;
#pragma unroll
  for (int i = 0; i < 4; ++i) {
#pragma unroll
    for (int j = 0; j < 4; ++j) {
      int row = m0 + wy * 64 + i * 16 + q4;
      int col = n0 + wx * 64 + j * 16 + rm;
      float bv = bias[col];
#pragma unroll
      for (int v = 0; v < 4; ++v) {
        float val = fmaxf(acc[i][j][v] + bv, 0.f);
        if constexpr (OUT_BF16) Cb[(size_t)(row + v) * N + col] = f2b(val);
        else                    Cf[(size_t)(row + v) * N + col] = val;
      }
    }
  }
}

// ====== fused gemm2 + mlp3: out = relu(g1@w2t + b2) @ w3 + b3 ======
// 2-phase K-loop (K=1024, N=128, 64 blocks). Epilogue stages the 128x128 g2
// tile (bf16, swizzled) into the dead As LDS, then a 4-deep MFMA chain
// against w3b [16][128] produces the final [128][9] f32 rows.
__global__ __launch_bounds__(256) void gemm2_fused(const unsigned short* __restrict__ A,
    const unsigned short* __restrict__ Bt, const unsigned short* __restrict__ w3b,
    const float* __restrict__ bias2, const float* __restrict__ b3,
    float* __restrict__ out) {
  __shared__ alignas(16) unsigned short As[2][128 * 64];
  __shared__ alignas(16) unsigned short Bs[2][128 * 64];
  const int tid = threadIdx.x;
  const int lane = tid & 63;
  const int wave = tid >> 6;
  const int wy = wave >> 1, wx = wave & 1;
  const int m0 = blockIdx.x * 128;
  const int K = 1024;

  f32x4 acc[4][4];
  const f32x4 z = {0.f, 0.f, 0.f, 0.f};
#pragma unroll
  for (int i = 0; i < 4; ++i)
#pragma unroll
    for (int j = 0; j < 4; ++j) acc[i][j] = z;

  const int srow = lane >> 3;
  const int sch  = (lane & 7) ^ srow;
  const int q    = lane >> 4;
  const int rm   = lane & 15;

#define STAGE2(buf, kk0)                                                             \
  {                                                                                  \
    _Pragma("unroll")                                                                \
    for (int t = 0; t < 4; ++t) {                                                    \
      int r0 = wave * 32 + t * 8;                                                    \
      const unsigned short* ga = A  + (size_t)(m0 + r0 + srow) * K + (kk0) + sch * 8;\
      const unsigned short* gb = Bt + (size_t)(r0 + srow) * K + (kk0) + sch * 8;     \
      __builtin_amdgcn_global_load_lds(                                              \
          (const __attribute__((address_space(1))) unsigned int*)(const void*)ga,    \
          (__attribute__((address_space(3))) unsigned int*)(void*)&As[buf][r0 * 64], \
          16, 0, 0);                                                                 \
      __builtin_amdgcn_global_load_lds(                                              \
          (const __attribute__((address_space(1))) unsigned int*)(const void*)gb,    \
          (__attribute__((address_space(3))) unsigned int*)(void*)&Bs[buf][r0 * 64], \
          16, 0, 0);                                                                 \
    }                                                                                \
  }

  STAGE2(0, 0);
  int cur = 0;
  for (int k0 = 0; k0 < K; k0 += 64) {
    if (k0 + 64 < K) {
      STAGE2(cur ^ 1, k0 + 64);
      asm volatile("s_waitcnt vmcnt(8)" ::: "memory");
    } else {
      asm volatile("s_waitcnt vmcnt(0)" ::: "memory");
    }
    __builtin_amdgcn_s_barrier();
#pragma unroll
    for (int kk = 0; kk < 2; ++kk) {
      bf16x8 af[4], bfr[4];
#pragma unroll
      for (int i = 0; i < 4; ++i) {
        int ra = wy * 64 + i * 16 + rm;
        int rb = wx * 64 + i * 16 + rm;
        af[i]  = *(const bf16x8*)&As[cur][ra * 64 + (((kk * 4 + q) ^ (ra & 7)) << 3)];
        bfr[i] = *(const bf16x8*)&Bs[cur][rb * 64 + (((kk * 4 + q) ^ (rb & 7)) << 3)];
      }
#pragma unroll
      for (int i = 0; i < 4; ++i)
#pragma unroll
        for (int j = 0; j < 4; ++j)
          acc[i][j] = __builtin_amdgcn_mfma_f32_16x16x32_bf16(af[i], bfr[j], acc[i][j], 0, 0, 0);
    }
    __builtin_amdgcn_s_barrier();
    cur ^= 1;
  }
#undef STAGE2

  // ---- stage g2 = relu(acc + b2) into As (bf16 [128][128], oct-swizzled) ----
  unsigned short* gs = &As[0][0];                // 32 KB, dead after K loop
  const int q4 = q * 4;
#pragma unroll
  for (int i = 0; i < 4; ++i) {
#pragma unroll
    for (int j = 0; j < 4; ++j) {
      int cl = wx * 64 + j * 16 + rm;            // local col 0..127
      float bv = bias2[cl];
#pragma unroll
      for (int v = 0; v < 4; ++v) {
        int r = wy * 64 + i * 16 + q4 + v;       // local row 0..127
        float val = fmaxf(acc[i][j][v] + bv, 0.f);
        gs[r * 128 + ((((cl >> 3) ^ (r & 7)) << 3) | (cl & 7))] = f2b(val);
      }
    }
  }
  __syncthreads();

  // ---- mini-GEMM: out_tile[128][9] = g2 @ w3 + b3 (each wave: 2 m-tiles) ----
  f32x4 a2[2];
#pragma unroll
  for (int i = 0; i < 2; ++i) a2[i] = z;
#pragma unroll
  for (int kt = 0; kt < 4; ++kt) {
    bf16x8 bW3 = *(const bf16x8*)&w3b[rm * 128 + kt * 32 + q * 8];
#pragma unroll
    for (int i = 0; i < 2; ++i) {
      int row = (wave * 2 + i) * 16 + rm;
      bf16x8 aG = *(const bf16x8*)&gs[row * 128 + (((kt * 4 + q) ^ (row & 7)) << 3)];
      a2[i] = __builtin_amdgcn_mfma_f32_16x16x32_bf16(aG, bW3, a2[i], 0, 0, 0);
    }
  }
#pragma unroll
  for (int i = 0; i < 2; ++i) {
    if (rm < 9) {
      float bv = b3[rm];
#pragma unroll
      for (int v = 0; v < 4; ++v) {
        int row = m0 + (wave * 2 + i) * 16 + q4 + v;
        out[(size_t)row * 9 + rm] = a2[i][v] + bv;
      }
    }
  }
}

// =========================== launch ===========================
extern "C" void kernel_launch(void* const* d_in, const int* in_sizes, int n_in,
                              void* d_out, int out_size, void* d_ws, size_t ws_size,
                              hipStream_t stream) {
  const float* x   = (const float*)d_in[0];
  const int*   ei  = (const int*)d_in[1];
  const float* W1  = (const float*)d_in[3];
  const float* as1 = (const float*)d_in[4];
  const float* ad1 = (const float*)d_in[5];
  const float* b1  = (const float*)d_in[6];
  const float* W2  = (const float*)d_in[7];
  const float* as2 = (const float*)d_in[8];
  const float* ad2 = (const float*)d_in[9];
  const float* b2  = (const float*)d_in[10];
  const float* W3  = (const float*)d_in[11];
  const float* as3 = (const float*)d_in[12];
  const float* ad3 = (const float*)d_in[13];
  const float* b3  = (const float*)d_in[14];
  const float* W4  = (const float*)d_in[15];
  const float* as4 = (const float*)d_in[16];
  const float* ad4 = (const float*)d_in[17];
  const float* b4  = (const float*)d_in[18];
  const float* lw1 = (const float*)d_in[19];
  const float* lb1 = (const float*)d_in[20];
  const float* lw2 = (const float*)d_in[21];
  const float* lb2 = (const float*)d_in[22];
  const float* lw3 = (const float*)d_in[23];
  const float* lb3 = (const float*)d_in[24];
  float* out = (float*)d_out;

  // workspace carve-up (bf16 stored as u16)
  unsigned short* f   = (unsigned short*)d_ws;            // [8192][4608] bf16
  unsigned short* w1t = f   + (size_t)NGRAPH * KP;        // [1024][4608] bf16
  unsigned short* w2t = w1t + (size_t)1024 * KP;          // [128][1024]  bf16
  unsigned short* g1  = w2t + (size_t)128 * 1024;         // [8192][1024] bf16
  // Wb lives in the old-g2 region (AFTER g1) so it survives gemm1's g1 write:
  // gemm2_fused reads w3b from it. ~16 KB of the 4 MB region.
  unsigned short* Wb  = g1 + (size_t)NGRAPH * 1024;

  prep_wb<<<1, 256, 0, stream>>>(W2, as2, ad2, W3, as3, ad3, W4, as4, ad4, lw3, Wb);
  tcast<true ><<<dim3(KP / 64, 1024 / 64), 256, 0, stream>>>(lw1, w1t, FDIM, 1024, KP);
  tcast<false><<<dim3(1024 / 64, 128 / 64), 256, 0, stream>>>(lw2, w2t, 1024, 128, 1024);

  gat_fused<<<NGRAPH, 64, 0, stream>>>(x, ei, W1, as1, ad1,
      b1, b2, b3, b4, Wb, f);

  mfma_gemm<true ><<<256, 512, 0, stream>>>(
      f, w1t, g1, nullptr, lb1, KP, 1024, 8);

  gemm2_fused<<<NGRAPH / 128, 256, 0, stream>>>(
      g1, w2t, Wb + 6144, lb2, lb3, out);
}

// Round 21
// 193.152 us; speedup vs baseline: 1.2194x; 1.0753x over previous
//
#include <hip/hip_runtime.h>

// Problem constants
#define NPG   39
#define NGRAPH 8192
#define EPG   312           // input edges per graph
#define EDG   351           // + 39 self loops
#define E0    2555904       // total input edges (8192*312)
#define FDIM  4560
#define KP    4608          // padded K for bf16 GEMM (multiple of 128)

typedef __bf16 bf16x8 __attribute__((ext_vector_type(8)));
typedef float  f32x4  __attribute__((ext_vector_type(4)));

__device__ __forceinline__ unsigned short f2b(float f) {
  unsigned int u = __float_as_uint(f);
  u += 0x7fffu + ((u >> 16) & 1u);            // RNE to bf16
  return (unsigned short)(u >> 16);
}
__device__ __forceinline__ unsigned int pk2(float lo, float hi) {
  return (unsigned int)f2b(lo) | ((unsigned int)f2b(hi) << 16);
}
__device__ __forceinline__ float b2f(unsigned short u) {
  return __uint_as_float((unsigned int)u << 16);
}
// wave-level "barrier": single wave per workgroup -> LDS drain + compiler fence
__device__ __forceinline__ void wsync() {
  asm volatile("s_waitcnt lgkmcnt(0)" ::: "memory");
}
// drain global stores (f_row RAW across layers, same CU)
__device__ __forceinline__ void gsync() {
  asm volatile("s_waitcnt vmcnt(0) lgkmcnt(0)" ::: "memory");
}

// =================== per-graph LDS (one wave per graph) ===================
__shared__ alignas(16) unsigned short Htb[32 * 64];      // 4096 B
__shared__ alignas(16) unsigned short alf16[40 * 64];    // 5120 B
__shared__ float sn[40];                                 // src attn scalars (alias: cnt)
__shared__ float dn[48];                                 // d-dot, then 1/den (pad 48)
__shared__ unsigned char csr_src[EDG + 1];
__shared__ unsigned short csr_ptr[NPG + 1];

// ======================= fused GAT layer (per wave) =======================
// INSRC: 0 = x register (L1), 1 = alf16 (prev layer staged), 2 = f_row.
// OUTDST: 0 = Htb staging (L2 halves, L4), 1 = alf16 staging (-> next layer).
template<int Fi, int Fo, int KPAD, int KT1, int NT, int HALVES,
         int DT, int SCOL, int DCOL, int INSRC, int OUTDST, bool GSYNC>
__device__ __forceinline__ void layerM(float x0,
                                       const unsigned short* __restrict__ Wb,
                                       const float* __restrict__ W1,
                                       const float* __restrict__ as1,
                                       const float* __restrict__ ad1,
                                       const float* __restrict__ bias,
                                       unsigned short* __restrict__ f_row,
                                       int in_off, int res_off, int out_off,
                                       int lane) {
  constexpr int NTH = NT / HALVES;
  constexpr int RMASK = (Fi >= 16) ? (Fi / 8 - 1) : 0;  // alf16 input swizzle
  constexpr int WMASK = (Fo >= 16) ? (Fo / 8 - 1) : 0;  // alf16 output swizzle
  constexpr int VW  = (HALVES == 2) ? 32 : Fo;          // Htb staging row width
  constexpr bool SWZST = (VW == 32);
  const int r15 = lane & 15, g = lane >> 4;
  const f32x4 z = {0.f, 0.f, 0.f, 0.f};
  const uint4 z4 = {0u, 0u, 0u, 0u};

  f32x4 c1[3][NT];                               // feature tiles (Fi>1)

  // ---------------- P1: c1 tiles + attention dot columns ----------------
  if constexpr (Fi == 1) {
    float was = 0.f, wad = 0.f;
#pragma unroll
    for (int o = 0; o < 8; ++o) { float w = W1[o]; was += w * as1[o]; wad += w * ad1[o]; }
    if (lane < NPG) {
      sn[lane] = x0 * was; dn[lane] = x0 * wad;
#pragma unroll
      for (int o = 0; o < 8; ++o) {              // Ht written directly
        int idx = o * 64 + ((((lane >> 3) ^ (o & 7)) << 3)) + (lane & 7);
        Htb[idx] = f2b(x0 * W1[o]);
      }
    }
  } else {
    if constexpr (GSYNC) gsync();                // L2's f flush must land
    f32x4 cd[3];
#pragma unroll
    for (int mt = 0; mt < 3; ++mt) cd[mt] = z;
#pragma unroll
    for (int mt = 0; mt < 3; ++mt)
#pragma unroll
      for (int nt = 0; nt < NT; ++nt) c1[mt][nt] = z;
    __builtin_amdgcn_s_setprio(1);
#pragma unroll
    for (int kt = 0; kt < KT1; ++kt) {
      bf16x8 aF[3];
#pragma unroll
      for (int mt = 0; mt < 3; ++mt) {
        int row = 16 * mt + r15;
        if constexpr (INSRC == 2) {
          row = (row > 39) ? 39 : row;           // never read uninit f bytes
          aF[mt] = *(const bf16x8*)&f_row[in_off + row * Fi + kt * 32 + g * 8];
        } else {
          aF[mt] = *(const bf16x8*)&alf16[row * Fi + (((kt * 4 + g) ^ (row & RMASK)) << 3)];
        }
      }
      if constexpr (DT >= NT) {                  // separate dot tile
        bf16x8 bD = *(const bf16x8*)&Wb[(16 * DT + r15) * KPAD + kt * 32 + g * 8];
#pragma unroll
        for (int mt = 0; mt < 3; ++mt)
          cd[mt] = __builtin_amdgcn_mfma_f32_16x16x32_bf16(aF[mt], bD, cd[mt], 0, 0, 0);
      }
#pragma unroll
      for (int nt = 0; nt < NT; ++nt) {
        bf16x8 bW = *(const bf16x8*)&Wb[(16 * nt + r15) * KPAD + kt * 32 + g * 8];
#pragma unroll
        for (int mt = 0; mt < 3; ++mt)
          c1[mt][nt] = __builtin_amdgcn_mfma_f32_16x16x32_bf16(aF[mt], bW, c1[mt][nt], 0, 0, 0);
      }
    }
    __builtin_amdgcn_s_setprio(0);
#pragma unroll
    for (int mt = 0; mt < 3; ++mt)
#pragma unroll
      for (int v = 0; v < 4; ++v) {
        float base = (DT >= NT) ? cd[mt][v] : c1[mt][DT][v];
        float t = base + __shfl_xor(base, 4);    // hi + lo column
        int r = 16 * mt + g * 4 + v;
        if (r15 == SCOL && r < NPG) sn[r] = t;
        if (r15 == DCOL && r < NPG) dn[r] = t;
      }
  }
  wsync();                                       // input consumed; sn/dn visible

  // ---- wave-global softmax shift (softmax is shift-invariant; lrelu is
  //      monotone so mg = lrelu(max sn + max dn) >= every e) ----
  float svm = (lane < NPG) ? sn[lane] : -3.4e38f;
  float dvm = (lane < NPG) ? dn[lane] : -3.4e38f;
#pragma unroll
  for (int st = 1; st < 64; st <<= 1) {
    svm = fmaxf(svm, __shfl_xor(svm, st));
    dvm = fmaxf(dvm, __shfl_xor(dvm, st));
  }
  float mg = svm + dvm;
  mg = (mg >= 0.f) ? mg : 0.2f * mg;

  // ---- zero alpha (deferred: input in alf16 already consumed into c1) ----
#pragma unroll
  for (int i = 0; i < 5; ++i) *(uint4*)&alf16[lane * 8 + i * 512] = z4;
  wsync();

  // ---- P3: per-dst softmax (single pass; global shift mg) ----
  if (lane < NPG) {
    int rs = csr_ptr[lane], re = csr_ptr[lane + 1];
    float dv = dn[lane];
    float den = 0.f;
    for (int k = rs; k < re; ++k) {
      int s = csr_src[k];
      float e = sn[s] + dv;
      e = (e >= 0.f) ? e : 0.2f * e;
      float w = __expf(e - mg);
      int idx = lane * 64 + ((((s >> 3) ^ (lane & 7)) << 3)) + (s & 7);
      float cur = b2f(alf16[idx]);               // duplicate edges accumulate
      unsigned short nb = f2b(cur + w);
      alf16[idx] = nb;
      den += b2f(nb) - cur;                      // den == sum of stored values
    }
    dn[lane] = 1.f / (den + 1e-16f);
  }
  wsync();

  // ---------------- P4: Out = alpha @ H via MFMA, per half ----------------
  float invr[3][4];
#pragma unroll
  for (int mt = 0; mt < 3; ++mt)
#pragma unroll
    for (int v = 0; v < 4; ++v) invr[mt][v] = dn[16 * mt + g * 4 + v];

  float pool_[NT];
#pragma unroll
  for (int s = 0; s < NT; ++s) pool_[s] = 0.f;

#pragma unroll
  for (int h = 0; h < HALVES; ++h) {
    const int colbase = (HALVES == 2) ? 32 * h : 0;
    if constexpr (Fi > 1) {                      // Ht from c1 registers
#pragma unroll
      for (int tl = 0; tl < NTH; ++tl) {
        int p = r15 + 16 * tl;
#pragma unroll
        for (int mt = 0; mt < 3; ++mt) {
          uint2 w;
          w.x = pk2(c1[mt][h * NTH + tl][0], c1[mt][h * NTH + tl][1]);
          w.y = pk2(c1[mt][h * NTH + tl][2], c1[mt][h * NTH + tl][3]);
          int idx = p * 64 + (((2 * mt + (g >> 1)) ^ (p & 7)) << 3) + (g & 1) * 4;
          *(uint2*)&Htb[idx] = w;
        }
      }
    }
    wsync();
    // alpha @ Ht
    f32x4 c2[3][NTH];
#pragma unroll
    for (int mt = 0; mt < 3; ++mt)
#pragma unroll
      for (int tl = 0; tl < NTH; ++tl) c2[mt][tl] = z;
    __builtin_amdgcn_s_setprio(1);
#pragma unroll
    for (int kt = 0; kt < 2; ++kt) {
      bf16x8 aA[3];
#pragma unroll
      for (int mt = 0; mt < 3; ++mt) {
        int row = 16 * mt + r15;
        aA[mt] = *(const bf16x8*)&alf16[row * 64 + ((((4 * kt + g) ^ (row & 7))) << 3)];
      }
#pragma unroll
      for (int tl = 0; tl < NTH; ++tl) {
        int p = r15 + 16 * tl;
        bf16x8 bH = *(const bf16x8*)&Htb[p * 64 + ((((4 * kt + g) ^ (p & 7))) << 3)];
#pragma unroll
        for (int mt = 0; mt < 3; ++mt)
          c2[mt][tl] = __builtin_amdgcn_mfma_f32_16x16x32_bf16(aA[mt], bH, c2[mt][tl], 0, 0, 0);
      }
    }
    __builtin_amdgcn_s_setprio(0);
    // epilogue: 1/den, bias, relu, stage (alpha/Ht dead post-c2), pool
#pragma unroll
    for (int tl = 0; tl < NTH; ++tl) {
      int c = r15 + 16 * (h * NTH + tl);
      float bv = (c < Fo) ? bias[c] : 0.f;
#pragma unroll
      for (int mt = 0; mt < 3; ++mt)
#pragma unroll
        for (int v = 0; v < 4; ++v) {
          int r = 16 * mt + g * 4 + v;
          float val = fmaxf(c2[mt][tl][v] * invr[mt][v] + bv, 0.f);
          if (r < NPG && c < Fo) {
            if constexpr (OUTDST == 1) {
              alf16[r * Fo + ((((c >> 3) ^ (r & WMASK)) << 3) | (c & 7))] = f2b(val);
            } else {
              int sc = c - colbase;
              int so = SWZST ? ((sc >> 3) ^ ((r >> 2) & 3)) : (sc >> 3);
              Htb[r * VW + (so << 3) + (sc & 7)] = f2b(val);
            }
            pool_[h * NTH + tl] = fmaxf(pool_[h * NTH + tl], val);
          }
        }
    }
    wsync();                                     // staging visible cross-lane

    // ---- residual flush: staging -> f_row, full 16B lines ----
    if constexpr (OUTDST == 1) {
      if constexpr (Fo == 8) {
        if (lane < NPG)
          *(uint4*)&f_row[res_off + lane * 8] = *(const uint4*)&alf16[lane * 8];
      } else {                                   // Fo == 32
        for (int j = lane; j < NPG * 4; j += 64) {
          int r = j >> 2, o = j & 3;
          *(uint4*)&f_row[res_off + r * 32 + 8 * o] =
              *(const uint4*)&alf16[r * 32 + ((o ^ (r & 3)) << 3)];
        }
      }
    } else if constexpr (Fo == 9) {
      for (int j = lane; j < 43; j += 64)
        *(uint4*)&f_row[res_off + j * 8] = *(const uint4*)&Htb[j * 8];
      if (lane < 7) f_row[res_off + 344 + lane] = Htb[344 + lane];
    } else {                                     // L2 halves (VW=32)
      for (int j = lane; j < NPG * 4; j += 64) {
        int r = j >> 2, o = j & 3;
        int so = o ^ ((r >> 2) & 3);
        *(uint4*)&f_row[res_off + r * Fo + colbase + 8 * o] =
            *(const uint4*)&Htb[r * VW + 8 * so];
      }
    }
    wsync();                                     // before next half's Ht writes
  }

  // ---- P5: per-graph max pool (cross-lane over row groups) ----
#pragma unroll
  for (int s = 0; s < NT; ++s) {
    float pv = pool_[s];
    pv = fmaxf(pv, __shfl_xor(pv, 16));
    pv = fmaxf(pv, __shfl_xor(pv, 32));
    int c = r15 + 16 * s;
    if (g == 0 && c < Fo) f_row[out_off + c] = f2b(pv);
  }
}

// =========================== fused GAT kernel ===========================
__global__ __launch_bounds__(64, 4) void gat_fused(
    const float* __restrict__ x, const int* __restrict__ ei,
    const float* __restrict__ W1, const float* __restrict__ as1, const float* __restrict__ ad1,
    const float* __restrict__ b1, const float* __restrict__ b2,
    const float* __restrict__ b3, const float* __restrict__ b4,
    const unsigned short* __restrict__ Wb,
    unsigned short* __restrict__ f) {
  const int b = blockIdx.x;
  const int lane = threadIdx.x;                    // one wave per graph
  const int base = b * NPG;
  const int* srcg = ei + (size_t)b * EPG;
  const int* dstg = ei + E0 + (size_t)b * EPG;
  unsigned short* f_row = f + (size_t)b * KP;
  int* cnt = (int*)sn;                             // alias: sn unused until layers
  const uint4 z4 = {0u, 0u, 0u, 0u};

  // zero Ht once (finite content guarantee for never-written node-cols 48-63)
#pragma unroll
  for (int i = 0; i < 4; ++i) *(uint4*)&Htb[lane * 8 + i * 512] = z4;

  // x load, res0, out0, zero columns (k=39 inserted zero col; 4561.. pad)
  float xv = 0.f;
  if (lane < NPG) {
    xv = x[(size_t)base + lane];
    f_row[lane] = f2b(xv);
  }
  if (lane == 0) f_row[39] = 0;
  if (lane < KP - 4561) f_row[4561 + lane] = 0;
  float mx = (lane < NPG) ? xv : -3.4e38f;
#pragma unroll
  for (int st = 1; st < 64; st <<= 1) { float t = __shfl_xor(mx, st); mx = fmaxf(mx, t); }
  if (lane == 0) f_row[4447] = f2b(mx);            // out0 = max over raw x
  if (lane < NPG) cnt[lane] = 1;                   // self loop pre-count
  wsync();

  // degree count (edges stashed in registers for the scatter pass)
  int es[5], ed[5];
#pragma unroll
  for (int it = 0; it < 5; ++it) {
    int e = lane + 64 * it;
    if (e < EPG) {
      int s = srcg[e] - base, d = dstg[e] - base;
      s = min(max(s, 0), NPG - 1);
      d = min(max(d, 0), NPG - 1);
      es[it] = s; ed[it] = d;
      atomicAdd(&cnt[d], 1);
    } else { es[it] = -1; ed[it] = 0; }
  }
  wsync();

  // exclusive prefix sum via wave scan (uniform control flow)
  int c = (lane < NPG) ? cnt[lane] : 0;
  int v = c;
#pragma unroll
  for (int off = 1; off < 64; off <<= 1) { int t = __shfl_up(v, off); if (lane >= off) v += t; }
  int excl = v - c;
  if (lane < NPG) csr_ptr[lane] = (unsigned short)excl;
  if (lane == NPG - 1) csr_ptr[NPG] = (unsigned short)EDG;
  wsync();
  if (lane < NPG) cnt[lane] = excl;                // running positions
  wsync();

  // scatter: self loops + edges
  if (lane < NPG) { int p = atomicAdd(&cnt[lane], 1); csr_src[p] = (unsigned char)lane; }
#pragma unroll
  for (int it = 0; it < 5; ++it) {
    if (es[it] >= 0) {
      int p = atomicAdd(&cnt[ed[it]], 1);
      p = min(p, EDG - 1);
      csr_src[p] = (unsigned char)es[it];
    }
  }
  wsync();

  const unsigned short* Wb2 = Wb;                  // [80][32]
  const unsigned short* Wb3 = Wb + 2560;           // [48][64]
  const unsigned short* Wb4 = Wb + 5632;           // [16][32]

  //      Fi  Fo KPAD KT1 NT HALV DT SCOL DCOL INSRC OUTDST GSYNC  in_off res  out
  layerM< 1,  8,  0,  0,  1,  1,  0,  0,  0,   0,    1,  false>(xv, nullptr, W1, as1, ad1, b1, f_row, 0,    40,   4448, lane);
  layerM< 8, 64, 32,  1,  4,  2,  4,  0,  1,   1,    0,  false>(0.f, Wb2, nullptr, nullptr, nullptr, b2, f_row, 0,    352,  4456, lane);
  layerM<64, 32, 64,  2,  2,  1,  2,  0,  1,   2,    1,  true >(0.f, Wb3, nullptr, nullptr, nullptr, b3, f_row, 352,  2848, 4520, lane);
  layerM<32,  9, 32,  1,  1,  1,  0, 10, 11,   1,    0,  false>(0.f, Wb4, nullptr, nullptr, nullptr, b4, f_row, 0,    4096, 4552, lane);
}

// ============ prep: W fragments (B^T layout) + attn-dot columns ============
__global__ __launch_bounds__(256) void prep_wb(
    const float* __restrict__ W2, const float* __restrict__ as2, const float* __restrict__ ad2,
    const float* __restrict__ W3, const float* __restrict__ as3, const float* __restrict__ ad3,
    const float* __restrict__ W4, const float* __restrict__ as4, const float* __restrict__ ad4,
    const float* __restrict__ w3mlp,
    unsigned short* __restrict__ Wb) {
  const int tid = threadIdx.x;
  for (int i = tid; i < 80 * 32; i += 256) {
    int o = i >> 5, k = i & 31; float v = 0.f;
    if (k < 8) {
      if (o < 64) v = W2[k * 64 + o];
      else if (o == 64 || o == 68) { float s = 0; for (int j = 0; j < 64; ++j) s += W2[k * 64 + j] * as2[j];
        float hi = b2f(f2b(s)); v = (o == 64) ? hi : (s - hi); }
      else if (o == 65 || o == 69) { float s = 0; for (int j = 0; j < 64; ++j) s += W2[k * 64 + j] * ad2[j];
        float hi = b2f(f2b(s)); v = (o == 65) ? hi : (s - hi); }
    }
    Wb[i] = f2b(v);
  }
  for (int i = tid; i < 48 * 64; i += 256) {
    int o = i >> 6, k = i & 63; float v = 0.f;
    if (o < 32) v = W3[k * 32 + o];
    else if (o == 32 || o == 36) { float s = 0; for (int j = 0; j < 32; ++j) s += W3[k * 32 + j] * as3[j];
      float hi = b2f(f2b(s)); v = (o == 32) ? hi : (s - hi); }
    else if (o == 33 || o == 37) { float s = 0; for (int j = 0; j < 32; ++j) s += W3[k * 32 + j] * ad3[j];
      float hi = b2f(f2b(s)); v = (o == 33) ? hi : (s - hi); }
    Wb[2560 + i] = f2b(v);
  }
  for (int i = tid; i < 16 * 32; i += 256) {
    int o = i >> 5, k = i & 31; float v = 0.f;
    if (o < 9) v = W4[k * 9 + o];
    else if (o == 10 || o == 14) { float s = 0; for (int j = 0; j < 9; ++j) s += W4[k * 9 + j] * as4[j];
      float hi = b2f(f2b(s)); v = (o == 10) ? hi : (s - hi); }
    else if (o == 11 || o == 15) { float s = 0; for (int j = 0; j < 9; ++j) s += W4[k * 9 + j] * ad4[j];
      float hi = b2f(f2b(s)); v = (o == 11) ? hi : (s - hi); }
    Wb[5632 + i] = f2b(v);
  }
  // w3 in B-fragment layout [16 cols][128 k] (cols 9..15 zero) at Wb+6144
  for (int i = tid; i < 16 * 128; i += 256) {
    int c = i >> 7, k = i & 127;
    Wb[6144 + i] = f2b((c < 9) ? w3mlp[k * 9 + c] : 0.f);
  }
}

// ================= weight transpose + bf16 cast (per launch) =================
template<bool PERM>
__global__ __launch_bounds__(256) void tcast(const float* __restrict__ in,
                                             unsigned short* __restrict__ out,
                                             int K, int NN, int Kpad) {
  __shared__ float tile[64 * 65];
  const int k0 = blockIdx.x * 64, n0 = blockIdx.y * 64;
  const int tid = threadIdx.x;
#pragma unroll
  for (int i = 0; i < 16; ++i) {
    int idx = i * 256 + tid;
    int r = idx >> 6, c = idx & 63;
    int k = k0 + r;
    int ko;
    if constexpr (PERM) {
      ko = (k < 39) ? k : ((k == 39 || k > FDIM) ? -1 : k - 1);
    } else {
      ko = (k < K) ? k : -1;
    }
    tile[r * 65 + c] = (ko >= 0) ? in[(size_t)ko * NN + n0 + c] : 0.f;
  }
  __syncthreads();
#pragma unroll
  for (int i = 0; i < 16; ++i) {
    int idx = i * 256 + tid;
    int r = idx >> 6, c = idx & 63;    // r: n-offset, c: k-offset
    out[(size_t)(n0 + r) * Kpad + k0 + c] = f2b(tile[c * 65 + r]);
  }
}

// ====== bf16 MFMA GEMM (128x128, BK=64, swizzled, XCD-clustered, 2-phase dbuf) ======
// Round-17 configuration: 4 waves, 512 blocks (2/CU), 8 loads/wave -> vmcnt(8).
template<bool OUT_BF16>
__global__ __launch_bounds__(256) void mfma_gemm(const unsigned short* __restrict__ A,
    const unsigned short* __restrict__ Bt, unsigned short* __restrict__ Cb,
    float* __restrict__ Cf, const float* __restrict__ bias, int K, int N, int gridN) {
  __shared__ alignas(16) unsigned short As[2][128 * 64];
  __shared__ alignas(16) unsigned short Bs[2][128 * 64];
  const int tid = threadIdx.x;
  const int lane = tid & 63;
  const int wave = tid >> 6;
  const int wy = wave >> 1, wx = wave & 1;

  const int wg = blockIdx.x;
  const int xcd = wg & 7, idx = wg >> 3;
  const int mpr = (int)(gridDim.x >> 3) / gridN;   // m-rows per XCD
  const int m_local = idx / gridN;
  const int n = idx - m_local * gridN;
  const int m0 = (xcd * mpr + m_local) * 128;
  const int n0 = n * 128;

  f32x4 acc[4][4];
  const f32x4 z = {0.f, 0.f, 0.f, 0.f};
#pragma unroll
  for (int i = 0; i < 4; ++i)
#pragma unroll
    for (int j = 0; j < 4; ++j) acc[i][j] = z;

  const int srow = lane >> 3;                  // row within 8-row store group
  const int sch  = (lane & 7) ^ srow;          // swizzled source 16B chunk
  const int q    = lane >> 4;                  // k sub-chunk 0..3
  const int rm   = lane & 15;

#define STAGE(buf, kk0)                                                              \
  {                                                                                  \
    _Pragma("unroll")                                                                \
    for (int t = 0; t < 4; ++t) {                                                    \
      int r0 = wave * 32 + t * 8;                                                    \
      const unsigned short* ga = A  + (size_t)(m0 + r0 + srow) * K + (kk0) + sch * 8;\
      const unsigned short* gb = Bt + (size_t)(n0 + r0 + srow) * K + (kk0) + sch * 8;\
      __builtin_amdgcn_global_load_lds(                                              \
          (const __attribute__((address_space(1))) unsigned int*)(const void*)ga,    \
          (__attribute__((address_space(3))) unsigned int*)(void*)&As[buf][r0 * 64], \
          16, 0, 0);                                                                 \
      __builtin_amdgcn_global_load_lds(                                              \
          (const __attribute__((address_space(1))) unsigned int*)(const void*)gb,    \
          (__attribute__((address_space(3))) unsigned int*)(void*)&Bs[buf][r0 * 64], \
          16, 0, 0);                                                                 \
    }                                                                                \
  }

  STAGE(0, 0);
  int cur = 0;
  for (int k0 = 0; k0 < K; k0 += 64) {
    if (k0 + 64 < K) {
      STAGE(cur ^ 1, k0 + 64);                 // prefetch next tile
      asm volatile("s_waitcnt vmcnt(8)" ::: "memory");   // current tile landed
    } else {
      asm volatile("s_waitcnt vmcnt(0)" ::: "memory");
    }
    __builtin_amdgcn_s_barrier();              // all waves' current loads done
#pragma unroll
    for (int kk = 0; kk < 2; ++kk) {
      bf16x8 af[4], bfr[4];
#pragma unroll
      for (int i = 0; i < 4; ++i) {
        int ra = wy * 64 + i * 16 + rm;
        int rb = wx * 64 + i * 16 + rm;
        af[i]  = *(const bf16x8*)&As[cur][ra * 64 + (((kk * 4 + q) ^ (ra & 7)) << 3)];
        bfr[i] = *(const bf16x8*)&Bs[cur][rb * 64 + (((kk * 4 + q) ^ (rb & 7)) << 3)];
      }
#pragma unroll
      for (int i = 0; i < 4; ++i)
#pragma unroll
        for (int j = 0; j < 4; ++j)
          acc[i][j] = __builtin_amdgcn_mfma_f32_16x16x32_bf16(af[i], bfr[j], acc[i][j], 0, 0, 0);
    }
    __builtin_amdgcn_s_barrier();              // reads done before next overwrite
    cur ^= 1;
  }
#undef STAGE

  const int q4 = (lane >> 4) * 4;
#pragma unroll
  for (int i = 0; i < 4; ++i) {
#pragma unroll
    for (int j = 0; j < 4; ++j) {
      int row = m0 + wy * 64 + i * 16 + q4;
      int col = n0 + wx * 64 + j * 16 + rm;
      float bv = bias[col];
#pragma unroll
      for (int v = 0; v < 4; ++v) {
        float val = fmaxf(acc[i][j][v] + bv, 0.f);
        if constexpr (OUT_BF16) Cb[(size_t)(row + v) * N + col] = f2b(val);
        else                    Cf[(size_t)(row + v) * N + col] = val;
      }
    }
  }
}

// ====== fused gemm2 + mlp3: out = relu(g1@w2t + b2) @ w3 + b3 ======
// 2-phase K-loop (K=1024, N=128, 64 blocks). Epilogue stages the 128x128 g2
// tile (bf16, swizzled) into the dead As LDS, then a 4-deep MFMA chain
// against w3b [16][128] produces the final [128][9] f32 rows.
__global__ __launch_bounds__(256) void gemm2_fused(const unsigned short* __restrict__ A,
    const unsigned short* __restrict__ Bt, const unsigned short* __restrict__ w3b,
    const float* __restrict__ bias2, const float* __restrict__ b3,
    float* __restrict__ out) {
  __shared__ alignas(16) unsigned short As[2][128 * 64];
  __shared__ alignas(16) unsigned short Bs[2][128 * 64];
  const int tid = threadIdx.x;
  const int lane = tid & 63;
  const int wave = tid >> 6;
  const int wy = wave >> 1, wx = wave & 1;
  const int m0 = blockIdx.x * 128;
  const int K = 1024;

  f32x4 acc[4][4];
  const f32x4 z = {0.f, 0.f, 0.f, 0.f};
#pragma unroll
  for (int i = 0; i < 4; ++i)
#pragma unroll
    for (int j = 0; j < 4; ++j) acc[i][j] = z;

  const int srow = lane >> 3;
  const int sch  = (lane & 7) ^ srow;
  const int q    = lane >> 4;
  const int rm   = lane & 15;

#define STAGE2(buf, kk0)                                                             \
  {                                                                                  \
    _Pragma("unroll")                                                                \
    for (int t = 0; t < 4; ++t) {                                                    \
      int r0 = wave * 32 + t * 8;                                                    \
      const unsigned short* ga = A  + (size_t)(m0 + r0 + srow) * K + (kk0) + sch * 8;\
      const unsigned short* gb = Bt + (size_t)(r0 + srow) * K + (kk0) + sch * 8;     \
      __builtin_amdgcn_global_load_lds(                                              \
          (const __attribute__((address_space(1))) unsigned int*)(const void*)ga,    \
          (__attribute__((address_space(3))) unsigned int*)(void*)&As[buf][r0 * 64], \
          16, 0, 0);                                                                 \
      __builtin_amdgcn_global_load_lds(                                              \
          (const __attribute__((address_space(1))) unsigned int*)(const void*)gb,    \
          (__attribute__((address_space(3))) unsigned int*)(void*)&Bs[buf][r0 * 64], \
          16, 0, 0);                                                                 \
    }                                                                                \
  }

  STAGE2(0, 0);
  int cur = 0;
  for (int k0 = 0; k0 < K; k0 += 64) {
    if (k0 + 64 < K) {
      STAGE2(cur ^ 1, k0 + 64);
      asm volatile("s_waitcnt vmcnt(8)" ::: "memory");
    } else {
      asm volatile("s_waitcnt vmcnt(0)" ::: "memory");
    }
    __builtin_amdgcn_s_barrier();
#pragma unroll
    for (int kk = 0; kk < 2; ++kk) {
      bf16x8 af[4], bfr[4];
#pragma unroll
      for (int i = 0; i < 4; ++i) {
        int ra = wy * 64 + i * 16 + rm;
        int rb = wx * 64 + i * 16 + rm;
        af[i]  = *(const bf16x8*)&As[cur][ra * 64 + (((kk * 4 + q) ^ (ra & 7)) << 3)];
        bfr[i] = *(const bf16x8*)&Bs[cur][rb * 64 + (((kk * 4 + q) ^ (rb & 7)) << 3)];
      }
#pragma unroll
      for (int i = 0; i < 4; ++i)
#pragma unroll
        for (int j = 0; j < 4; ++j)
          acc[i][j] = __builtin_amdgcn_mfma_f32_16x16x32_bf16(af[i], bfr[j], acc[i][j], 0, 0, 0);
    }
    __builtin_amdgcn_s_barrier();
    cur ^= 1;
  }
#undef STAGE2

  // ---- stage g2 = relu(acc + b2) into As (bf16 [128][128], oct-swizzled) ----
  unsigned short* gs = &As[0][0];                // 32 KB, dead after K loop
  const int q4 = q * 4;
#pragma unroll
  for (int i = 0; i < 4; ++i) {
#pragma unroll
    for (int j = 0; j < 4; ++j) {
      int cl = wx * 64 + j * 16 + rm;            // local col 0..127
      float bv = bias2[cl];
#pragma unroll
      for (int v = 0; v < 4; ++v) {
        int r = wy * 64 + i * 16 + q4 + v;       // local row 0..127
        float val = fmaxf(acc[i][j][v] + bv, 0.f);
        gs[r * 128 + ((((cl >> 3) ^ (r & 7)) << 3) | (cl & 7))] = f2b(val);
      }
    }
  }
  __syncthreads();

  // ---- mini-GEMM: out_tile[128][9] = g2 @ w3 + b3 (each wave: 2 m-tiles) ----
  f32x4 a2[2];
#pragma unroll
  for (int i = 0; i < 2; ++i) a2[i] = z;
#pragma unroll
  for (int kt = 0; kt < 4; ++kt) {
    bf16x8 bW3 = *(const bf16x8*)&w3b[rm * 128 + kt * 32 + q * 8];
#pragma unroll
    for (int i = 0; i < 2; ++i) {
      int row = (wave * 2 + i) * 16 + rm;
      bf16x8 aG = *(const bf16x8*)&gs[row * 128 + (((kt * 4 + q) ^ (row & 7)) << 3)];
      a2[i] = __builtin_amdgcn_mfma_f32_16x16x32_bf16(aG, bW3, a2[i], 0, 0, 0);
    }
  }
#pragma unroll
  for (int i = 0; i < 2; ++i) {
    if (rm < 9) {
      float bv = b3[rm];
#pragma unroll
      for (int v = 0; v < 4; ++v) {
        int row = m0 + (wave * 2 + i) * 16 + q4 + v;
        out[(size_t)row * 9 + rm] = a2[i][v] + bv;
      }
    }
  }
}

// =========================== launch ===========================
extern "C" void kernel_launch(void* const* d_in, const int* in_sizes, int n_in,
                              void* d_out, int out_size, void* d_ws, size_t ws_size,
                              hipStream_t stream) {
  const float* x   = (const float*)d_in[0];
  const int*   ei  = (const int*)d_in[1];
  const float* W1  = (const float*)d_in[3];
  const float* as1 = (const float*)d_in[4];
  const float* ad1 = (const float*)d_in[5];
  const float* b1  = (const float*)d_in[6];
  const float* W2  = (const float*)d_in[7];
  const float* as2 = (const float*)d_in[8];
  const float* ad2 = (const float*)d_in[9];
  const float* b2  = (const float*)d_in[10];
  const float* W3  = (const float*)d_in[11];
  const float* as3 = (const float*)d_in[12];
  const float* ad3 = (const float*)d_in[13];
  const float* b3  = (const float*)d_in[14];
  const float* W4  = (const float*)d_in[15];
  const float* as4 = (const float*)d_in[16];
  const float* ad4 = (const float*)d_in[17];
  const float* b4  = (const float*)d_in[18];
  const float* lw1 = (const float*)d_in[19];
  const float* lb1 = (const float*)d_in[20];
  const float* lw2 = (const float*)d_in[21];
  const float* lb2 = (const float*)d_in[22];
  const float* lw3 = (const float*)d_in[23];
  const float* lb3 = (const float*)d_in[24];
  float* out = (float*)d_out;

  // workspace carve-up (bf16 stored as u16)
  unsigned short* f   = (unsigned short*)d_ws;            // [8192][4608] bf16
  unsigned short* w1t = f   + (size_t)NGRAPH * KP;        // [1024][4608] bf16
  unsigned short* w2t = w1t + (size_t)1024 * KP;          // [128][1024]  bf16
  unsigned short* g1  = w2t + (size_t)128 * 1024;         // [8192][1024] bf16
  // Wb lives in the old-g2 region (AFTER g1) so it survives gemm1's g1 write:
  // gemm2_fused reads w3b from it. ~16 KB of the 4 MB region.
  unsigned short* Wb  = g1 + (size_t)NGRAPH * 1024;

  prep_wb<<<1, 256, 0, stream>>>(W2, as2, ad2, W3, as3, ad3, W4, as4, ad4, lw3, Wb);
  tcast<true ><<<dim3(KP / 64, 1024 / 64), 256, 0, stream>>>(lw1, w1t, FDIM, 1024, KP);
  tcast<false><<<dim3(1024 / 64, 128 / 64), 256, 0, stream>>>(lw2, w2t, 1024, 128, 1024);

  gat_fused<<<NGRAPH, 64, 0, stream>>>(x, ei, W1, as1, ad1,
      b1, b2, b3, b4, Wb, f);

  mfma_gemm<true ><<<512, 256, 0, stream>>>(
      f, w1t, g1, nullptr, lb1, KP, 1024, 8);

  gemm2_fused<<<NGRAPH / 128, 256, 0, stream>>>(
      g1, w2t, Wb + 6144, lb2, lb3, out);
}

// Round 22
// 188.161 us; speedup vs baseline: 1.2517x; 1.0265x over previous
//
#include <hip/hip_runtime.h>

// Problem constants
#define NPG   39
#define NGRAPH 8192
#define EPG   312           // input edges per graph
#define EDG   351           // + 39 self loops
#define E0    2555904       // total input edges (8192*312)
#define FDIM  4560
#define KP    4608          // padded K for bf16 GEMM (multiple of 128)

typedef __bf16 bf16x8 __attribute__((ext_vector_type(8)));
typedef float  f32x4  __attribute__((ext_vector_type(4)));

__device__ __forceinline__ unsigned short f2b(float f) {
  unsigned int u = __float_as_uint(f);
  u += 0x7fffu + ((u >> 16) & 1u);            // RNE to bf16
  return (unsigned short)(u >> 16);
}
__device__ __forceinline__ unsigned int pk2(float lo, float hi) {
  return (unsigned int)f2b(lo) | ((unsigned int)f2b(hi) << 16);
}
__device__ __forceinline__ float b2f(unsigned short u) {
  return __uint_as_float((unsigned int)u << 16);
}
// wave-level "barrier": single wave per workgroup -> LDS drain + compiler fence
__device__ __forceinline__ void wsync() {
  asm volatile("s_waitcnt lgkmcnt(0)" ::: "memory");
}
// drain global stores (f_row RAW across layers, same CU)
__device__ __forceinline__ void gsync() {
  asm volatile("s_waitcnt vmcnt(0) lgkmcnt(0)" ::: "memory");
}

// =================== per-graph LDS (one wave per graph) ===================
__shared__ alignas(16) unsigned short Htb[32 * 64];      // 4096 B
__shared__ alignas(16) unsigned short alf16[40 * 64];    // 5120 B
__shared__ float sn[40];                                 // src attn scalars (alias: cnt)
__shared__ float dn[48];                                 // d-dot, then 1/den (pad 48)
__shared__ unsigned char csr_src[EDG + 1];
__shared__ unsigned short csr_ptr[NPG + 1];

// ======================= fused GAT layer (per wave) =======================
// INSRC: 0 = x register (L1), 1 = alf16 (prev layer staged), 2 = f_row.
// OUTDST: 0 = Htb staging (L2 halves, L4), 1 = alf16 staging (-> next layer).
template<int Fi, int Fo, int KPAD, int KT1, int NT, int HALVES,
         int DT, int SCOL, int DCOL, int INSRC, int OUTDST, bool GSYNC>
__device__ __forceinline__ void layerM(float x0,
                                       const unsigned short* __restrict__ Wb,
                                       const float* __restrict__ W1,
                                       const float* __restrict__ as1,
                                       const float* __restrict__ ad1,
                                       const float* __restrict__ bias,
                                       unsigned short* __restrict__ f_row,
                                       int in_off, int res_off, int out_off,
                                       int lane) {
  constexpr int NTH = NT / HALVES;
  constexpr int RMASK = (Fi >= 16) ? (Fi / 8 - 1) : 0;  // alf16 input swizzle
  constexpr int WMASK = (Fo >= 16) ? (Fo / 8 - 1) : 0;  // alf16 output swizzle
  constexpr int VW  = (HALVES == 2) ? 32 : Fo;          // Htb staging row width
  constexpr bool SWZST = (VW == 32);
  const int r15 = lane & 15, g = lane >> 4;
  const f32x4 z = {0.f, 0.f, 0.f, 0.f};
  const uint4 z4 = {0u, 0u, 0u, 0u};

  f32x4 c1[3][NT];                               // feature tiles (Fi>1)

  // ---------------- P1: c1 tiles + attention dot columns ----------------
  if constexpr (Fi == 1) {
    float was = 0.f, wad = 0.f;
#pragma unroll
    for (int o = 0; o < 8; ++o) { float w = W1[o]; was += w * as1[o]; wad += w * ad1[o]; }
    if (lane < NPG) {
      sn[lane] = x0 * was; dn[lane] = x0 * wad;
#pragma unroll
      for (int o = 0; o < 8; ++o) {              // Ht written directly
        int idx = o * 64 + ((((lane >> 3) ^ (o & 7)) << 3)) + (lane & 7);
        Htb[idx] = f2b(x0 * W1[o]);
      }
    }
  } else {
    if constexpr (GSYNC) gsync();                // L2's f flush must land
    f32x4 cd[3];
#pragma unroll
    for (int mt = 0; mt < 3; ++mt) cd[mt] = z;
#pragma unroll
    for (int mt = 0; mt < 3; ++mt)
#pragma unroll
      for (int nt = 0; nt < NT; ++nt) c1[mt][nt] = z;
    __builtin_amdgcn_s_setprio(1);
#pragma unroll
    for (int kt = 0; kt < KT1; ++kt) {
      bf16x8 aF[3];
#pragma unroll
      for (int mt = 0; mt < 3; ++mt) {
        int row = 16 * mt + r15;
        if constexpr (INSRC == 2) {
          row = (row > 39) ? 39 : row;           // never read uninit f bytes
          aF[mt] = *(const bf16x8*)&f_row[in_off + row * Fi + kt * 32 + g * 8];
        } else {
          aF[mt] = *(const bf16x8*)&alf16[row * Fi + (((kt * 4 + g) ^ (row & RMASK)) << 3)];
        }
      }
      if constexpr (DT >= NT) {                  // separate dot tile
        bf16x8 bD = *(const bf16x8*)&Wb[(16 * DT + r15) * KPAD + kt * 32 + g * 8];
#pragma unroll
        for (int mt = 0; mt < 3; ++mt)
          cd[mt] = __builtin_amdgcn_mfma_f32_16x16x32_bf16(aF[mt], bD, cd[mt], 0, 0, 0);
      }
#pragma unroll
      for (int nt = 0; nt < NT; ++nt) {
        bf16x8 bW = *(const bf16x8*)&Wb[(16 * nt + r15) * KPAD + kt * 32 + g * 8];
#pragma unroll
        for (int mt = 0; mt < 3; ++mt)
          c1[mt][nt] = __builtin_amdgcn_mfma_f32_16x16x32_bf16(aF[mt], bW, c1[mt][nt], 0, 0, 0);
      }
    }
    __builtin_amdgcn_s_setprio(0);
#pragma unroll
    for (int mt = 0; mt < 3; ++mt)
#pragma unroll
      for (int v = 0; v < 4; ++v) {
        float base = (DT >= NT) ? cd[mt][v] : c1[mt][DT][v];
        float t = base + __shfl_xor(base, 4);    // hi + lo column
        int r = 16 * mt + g * 4 + v;
        if (r15 == SCOL && r < NPG) sn[r] = t;
        if (r15 == DCOL && r < NPG) dn[r] = t;
      }
  }
  wsync();                                       // input consumed; sn/dn visible

  // ---- wave-global softmax shift (softmax is shift-invariant; lrelu is
  //      monotone so mg = lrelu(max sn + max dn) >= every e) ----
  float svm = (lane < NPG) ? sn[lane] : -3.4e38f;
  float dvm = (lane < NPG) ? dn[lane] : -3.4e38f;
#pragma unroll
  for (int st = 1; st < 64; st <<= 1) {
    svm = fmaxf(svm, __shfl_xor(svm, st));
    dvm = fmaxf(dvm, __shfl_xor(dvm, st));
  }
  float mg = svm + dvm;
  mg = (mg >= 0.f) ? mg : 0.2f * mg;

  // ---- zero alpha (deferred: input in alf16 already consumed into c1) ----
#pragma unroll
  for (int i = 0; i < 5; ++i) *(uint4*)&alf16[lane * 8 + i * 512] = z4;
  wsync();

  // ---- P3: per-dst softmax (single pass; global shift mg) ----
  if (lane < NPG) {
    int rs = csr_ptr[lane], re = csr_ptr[lane + 1];
    float dv = dn[lane];
    float den = 0.f;
    for (int k = rs; k < re; ++k) {
      int s = csr_src[k];
      float e = sn[s] + dv;
      e = (e >= 0.f) ? e : 0.2f * e;
      float w = __expf(e - mg);
      int idx = lane * 64 + ((((s >> 3) ^ (lane & 7)) << 3)) + (s & 7);
      float cur = b2f(alf16[idx]);               // duplicate edges accumulate
      unsigned short nb = f2b(cur + w);
      alf16[idx] = nb;
      den += b2f(nb) - cur;                      // den == sum of stored values
    }
    dn[lane] = 1.f / (den + 1e-16f);
  }
  wsync();

  // ---------------- P4: Out = alpha @ H via MFMA, per half ----------------
  float invr[3][4];
#pragma unroll
  for (int mt = 0; mt < 3; ++mt)
#pragma unroll
    for (int v = 0; v < 4; ++v) invr[mt][v] = dn[16 * mt + g * 4 + v];

  float pool_[NT];
#pragma unroll
  for (int s = 0; s < NT; ++s) pool_[s] = 0.f;

#pragma unroll
  for (int h = 0; h < HALVES; ++h) {
    const int colbase = (HALVES == 2) ? 32 * h : 0;
    if constexpr (Fi > 1) {                      // Ht from c1 registers
#pragma unroll
      for (int tl = 0; tl < NTH; ++tl) {
        int p = r15 + 16 * tl;
#pragma unroll
        for (int mt = 0; mt < 3; ++mt) {
          uint2 w;
          w.x = pk2(c1[mt][h * NTH + tl][0], c1[mt][h * NTH + tl][1]);
          w.y = pk2(c1[mt][h * NTH + tl][2], c1[mt][h * NTH + tl][3]);
          int idx = p * 64 + (((2 * mt + (g >> 1)) ^ (p & 7)) << 3) + (g & 1) * 4;
          *(uint2*)&Htb[idx] = w;
        }
      }
    }
    wsync();
    // alpha @ Ht
    f32x4 c2[3][NTH];
#pragma unroll
    for (int mt = 0; mt < 3; ++mt)
#pragma unroll
      for (int tl = 0; tl < NTH; ++tl) c2[mt][tl] = z;
    __builtin_amdgcn_s_setprio(1);
#pragma unroll
    for (int kt = 0; kt < 2; ++kt) {
      bf16x8 aA[3];
#pragma unroll
      for (int mt = 0; mt < 3; ++mt) {
        int row = 16 * mt + r15;
        aA[mt] = *(const bf16x8*)&alf16[row * 64 + ((((4 * kt + g) ^ (row & 7))) << 3)];
      }
#pragma unroll
      for (int tl = 0; tl < NTH; ++tl) {
        int p = r15 + 16 * tl;
        bf16x8 bH = *(const bf16x8*)&Htb[p * 64 + ((((4 * kt + g) ^ (p & 7))) << 3)];
#pragma unroll
        for (int mt = 0; mt < 3; ++mt)
          c2[mt][tl] = __builtin_amdgcn_mfma_f32_16x16x32_bf16(aA[mt], bH, c2[mt][tl], 0, 0, 0);
      }
    }
    __builtin_amdgcn_s_setprio(0);
    // epilogue: 1/den, bias, relu, stage (alpha/Ht dead post-c2), pool
#pragma unroll
    for (int tl = 0; tl < NTH; ++tl) {
      int c = r15 + 16 * (h * NTH + tl);
      float bv = (c < Fo) ? bias[c] : 0.f;
#pragma unroll
      for (int mt = 0; mt < 3; ++mt)
#pragma unroll
        for (int v = 0; v < 4; ++v) {
          int r = 16 * mt + g * 4 + v;
          float val = fmaxf(c2[mt][tl][v] * invr[mt][v] + bv, 0.f);
          if (r < NPG && c < Fo) {
            if constexpr (OUTDST == 1) {
              alf16[r * Fo + ((((c >> 3) ^ (r & WMASK)) << 3) | (c & 7))] = f2b(val);
            } else {
              int sc = c - colbase;
              int so = SWZST ? ((sc >> 3) ^ ((r >> 2) & 3)) : (sc >> 3);
              Htb[r * VW + (so << 3) + (sc & 7)] = f2b(val);
            }
            pool_[h * NTH + tl] = fmaxf(pool_[h * NTH + tl], val);
          }
        }
    }
    wsync();                                     // staging visible cross-lane

    // ---- residual flush: staging -> f_row, full 16B lines ----
    if constexpr (OUTDST == 1) {
      if constexpr (Fo == 8) {
        if (lane < NPG)
          *(uint4*)&f_row[res_off + lane * 8] = *(const uint4*)&alf16[lane * 8];
      } else {                                   // Fo == 32
        for (int j = lane; j < NPG * 4; j += 64) {
          int r = j >> 2, o = j & 3;
          *(uint4*)&f_row[res_off + r * 32 + 8 * o] =
              *(const uint4*)&alf16[r * 32 + ((o ^ (r & 3)) << 3)];
        }
      }
    } else if constexpr (Fo == 9) {
      for (int j = lane; j < 43; j += 64)
        *(uint4*)&f_row[res_off + j * 8] = *(const uint4*)&Htb[j * 8];
      if (lane < 7) f_row[res_off + 344 + lane] = Htb[344 + lane];
    } else {                                     // L2 halves (VW=32)
      for (int j = lane; j < NPG * 4; j += 64) {
        int r = j >> 2, o = j & 3;
        int so = o ^ ((r >> 2) & 3);
        *(uint4*)&f_row[res_off + r * Fo + colbase + 8 * o] =
            *(const uint4*)&Htb[r * VW + 8 * so];
      }
    }
    wsync();                                     // before next half's Ht writes
  }

  // ---- P5: per-graph max pool (cross-lane over row groups) ----
#pragma unroll
  for (int s = 0; s < NT; ++s) {
    float pv = pool_[s];
    pv = fmaxf(pv, __shfl_xor(pv, 16));
    pv = fmaxf(pv, __shfl_xor(pv, 32));
    int c = r15 + 16 * s;
    if (g == 0 && c < Fo) f_row[out_off + c] = f2b(pv);
  }
}

// =========================== fused GAT kernel ===========================
__global__ __launch_bounds__(64, 4) void gat_fused(
    const float* __restrict__ x, const int* __restrict__ ei,
    const float* __restrict__ W1, const float* __restrict__ as1, const float* __restrict__ ad1,
    const float* __restrict__ b1, const float* __restrict__ b2,
    const float* __restrict__ b3, const float* __restrict__ b4,
    const unsigned short* __restrict__ Wb,
    unsigned short* __restrict__ f) {
  const int b = blockIdx.x;
  const int lane = threadIdx.x;                    // one wave per graph
  const int base = b * NPG;
  const int* srcg = ei + (size_t)b * EPG;
  const int* dstg = ei + E0 + (size_t)b * EPG;
  unsigned short* f_row = f + (size_t)b * KP;
  int* cnt = (int*)sn;                             // alias: sn unused until layers
  const uint4 z4 = {0u, 0u, 0u, 0u};

  // zero Ht once (finite content guarantee for never-written node-cols 48-63)
#pragma unroll
  for (int i = 0; i < 4; ++i) *(uint4*)&Htb[lane * 8 + i * 512] = z4;

  // x load, res0, out0, zero columns (k=39 inserted zero col; 4561.. pad)
  float xv = 0.f;
  if (lane < NPG) {
    xv = x[(size_t)base + lane];
    f_row[lane] = f2b(xv);
  }
  if (lane == 0) f_row[39] = 0;
  if (lane < KP - 4561) f_row[4561 + lane] = 0;
  float mx = (lane < NPG) ? xv : -3.4e38f;
#pragma unroll
  for (int st = 1; st < 64; st <<= 1) { float t = __shfl_xor(mx, st); mx = fmaxf(mx, t); }
  if (lane == 0) f_row[4447] = f2b(mx);            // out0 = max over raw x
  if (lane < NPG) cnt[lane] = 1;                   // self loop pre-count
  wsync();

  // degree count (edges stashed in registers for the scatter pass)
  int es[5], ed[5];
#pragma unroll
  for (int it = 0; it < 5; ++it) {
    int e = lane + 64 * it;
    if (e < EPG) {
      int s = srcg[e] - base, d = dstg[e] - base;
      s = min(max(s, 0), NPG - 1);
      d = min(max(d, 0), NPG - 1);
      es[it] = s; ed[it] = d;
      atomicAdd(&cnt[d], 1);
    } else { es[it] = -1; ed[it] = 0; }
  }
  wsync();

  // exclusive prefix sum via wave scan (uniform control flow)
  int c = (lane < NPG) ? cnt[lane] : 0;
  int v = c;
#pragma unroll
  for (int off = 1; off < 64; off <<= 1) { int t = __shfl_up(v, off); if (lane >= off) v += t; }
  int excl = v - c;
  if (lane < NPG) csr_ptr[lane] = (unsigned short)excl;
  if (lane == NPG - 1) csr_ptr[NPG] = (unsigned short)EDG;
  wsync();
  if (lane < NPG) cnt[lane] = excl;                // running positions
  wsync();

  // scatter: self loops + edges
  if (lane < NPG) { int p = atomicAdd(&cnt[lane], 1); csr_src[p] = (unsigned char)lane; }
#pragma unroll
  for (int it = 0; it < 5; ++it) {
    if (es[it] >= 0) {
      int p = atomicAdd(&cnt[ed[it]], 1);
      p = min(p, EDG - 1);
      csr_src[p] = (unsigned char)es[it];
    }
  }
  wsync();

  const unsigned short* Wb2 = Wb;                  // [80][32]
  const unsigned short* Wb3 = Wb + 2560;           // [48][64]
  const unsigned short* Wb4 = Wb + 5632;           // [16][32]

  //      Fi  Fo KPAD KT1 NT HALV DT SCOL DCOL INSRC OUTDST GSYNC  in_off res  out
  layerM< 1,  8,  0,  0,  1,  1,  0,  0,  0,   0,    1,  false>(xv, nullptr, W1, as1, ad1, b1, f_row, 0,    40,   4448, lane);
  layerM< 8, 64, 32,  1,  4,  2,  4,  0,  1,   1,    0,  false>(0.f, Wb2, nullptr, nullptr, nullptr, b2, f_row, 0,    352,  4456, lane);
  layerM<64, 32, 64,  2,  2,  1,  2,  0,  1,   2,    1,  true >(0.f, Wb3, nullptr, nullptr, nullptr, b3, f_row, 352,  2848, 4520, lane);
  layerM<32,  9, 32,  1,  1,  1,  0, 10, 11,   1,    0,  false>(0.f, Wb4, nullptr, nullptr, nullptr, b4, f_row, 0,    4096, 4552, lane);
}

// ============ prep: W fragments (B^T layout) + attn-dot columns ============
__global__ __launch_bounds__(256) void prep_wb(
    const float* __restrict__ W2, const float* __restrict__ as2, const float* __restrict__ ad2,
    const float* __restrict__ W3, const float* __restrict__ as3, const float* __restrict__ ad3,
    const float* __restrict__ W4, const float* __restrict__ as4, const float* __restrict__ ad4,
    const float* __restrict__ w3mlp,
    unsigned short* __restrict__ Wb) {
  const int tid = threadIdx.x;
  for (int i = tid; i < 80 * 32; i += 256) {
    int o = i >> 5, k = i & 31; float v = 0.f;
    if (k < 8) {
      if (o < 64) v = W2[k * 64 + o];
      else if (o == 64 || o == 68) { float s = 0; for (int j = 0; j < 64; ++j) s += W2[k * 64 + j] * as2[j];
        float hi = b2f(f2b(s)); v = (o == 64) ? hi : (s - hi); }
      else if (o == 65 || o == 69) { float s = 0; for (int j = 0; j < 64; ++j) s += W2[k * 64 + j] * ad2[j];
        float hi = b2f(f2b(s)); v = (o == 65) ? hi : (s - hi); }
    }
    Wb[i] = f2b(v);
  }
  for (int i = tid; i < 48 * 64; i += 256) {
    int o = i >> 6, k = i & 63; float v = 0.f;
    if (o < 32) v = W3[k * 32 + o];
    else if (o == 32 || o == 36) { float s = 0; for (int j = 0; j < 32; ++j) s += W3[k * 32 + j] * as3[j];
      float hi = b2f(f2b(s)); v = (o == 32) ? hi : (s - hi); }
    else if (o == 33 || o == 37) { float s = 0; for (int j = 0; j < 32; ++j) s += W3[k * 32 + j] * ad3[j];
      float hi = b2f(f2b(s)); v = (o == 33) ? hi : (s - hi); }
    Wb[2560 + i] = f2b(v);
  }
  for (int i = tid; i < 16 * 32; i += 256) {
    int o = i >> 5, k = i & 31; float v = 0.f;
    if (o < 9) v = W4[k * 9 + o];
    else if (o == 10 || o == 14) { float s = 0; for (int j = 0; j < 9; ++j) s += W4[k * 9 + j] * as4[j];
      float hi = b2f(f2b(s)); v = (o == 10) ? hi : (s - hi); }
    else if (o == 11 || o == 15) { float s = 0; for (int j = 0; j < 9; ++j) s += W4[k * 9 + j] * ad4[j];
      float hi = b2f(f2b(s)); v = (o == 11) ? hi : (s - hi); }
    Wb[5632 + i] = f2b(v);
  }
  // w3 in B-fragment layout [16 cols][128 k] (cols 9..15 zero) at Wb+6144
  for (int i = tid; i < 16 * 128; i += 256) {
    int c = i >> 7, k = i & 127;
    Wb[6144 + i] = f2b((c < 9) ? w3mlp[k * 9 + c] : 0.f);
  }
}

// ================= weight transpose + bf16 cast (per launch) =================
template<bool PERM>
__global__ __launch_bounds__(256) void tcast(const float* __restrict__ in,
                                             unsigned short* __restrict__ out,
                                             int K, int NN, int Kpad) {
  __shared__ float tile[64 * 65];
  const int k0 = blockIdx.x * 64, n0 = blockIdx.y * 64;
  const int tid = threadIdx.x;
#pragma unroll
  for (int i = 0; i < 16; ++i) {
    int idx = i * 256 + tid;
    int r = idx >> 6, c = idx & 63;
    int k = k0 + r;
    int ko;
    if constexpr (PERM) {
      ko = (k < 39) ? k : ((k == 39 || k > FDIM) ? -1 : k - 1);
    } else {
      ko = (k < K) ? k : -1;
    }
    tile[r * 65 + c] = (ko >= 0) ? in[(size_t)ko * NN + n0 + c] : 0.f;
  }
  __syncthreads();
#pragma unroll
  for (int i = 0; i < 16; ++i) {
    int idx = i * 256 + tid;
    int r = idx >> 6, c = idx & 63;    // r: n-offset, c: k-offset
    out[(size_t)(n0 + r) * Kpad + k0 + c] = f2b(tile[c * 65 + r]);
  }
}

// ====== bf16 MFMA GEMM (128x128, BK=64, swizzled, XCD-clustered, 2-phase dbuf) ======
// Round-17 configuration: 4 waves, 512 blocks (2/CU), 8 loads/wave -> vmcnt(8).
template<bool OUT_BF16>
__global__ __launch_bounds__(256) void mfma_gemm(const unsigned short* __restrict__ A,
    const unsigned short* __restrict__ Bt, unsigned short* __restrict__ Cb,
    float* __restrict__ Cf, const float* __restrict__ bias, int K, int N, int gridN) {
  __shared__ alignas(16) unsigned short As[2][128 * 64];
  __shared__ alignas(16) unsigned short Bs[2][128 * 64];
  const int tid = threadIdx.x;
  const int lane = tid & 63;
  const int wave = tid >> 6;
  const int wy = wave >> 1, wx = wave & 1;

  const int wg = blockIdx.x;
  const int xcd = wg & 7, idx = wg >> 3;
  const int mpr = (int)(gridDim.x >> 3) / gridN;   // m-rows per XCD
  const int m_local = idx / gridN;
  const int n = idx - m_local * gridN;
  const int m0 = (xcd * mpr + m_local) * 128;
  const int n0 = n * 128;

  f32x4 acc[4][4];
  const f32x4 z = {0.f, 0.f, 0.f, 0.f};
#pragma unroll
  for (int i = 0; i < 4; ++i)
#pragma unroll
    for (int j = 0; j < 4; ++j) acc[i][j] = z;

  const int srow = lane >> 3;                  // row within 8-row store group
  const int sch  = (lane & 7) ^ srow;          // swizzled source 16B chunk
  const int q    = lane >> 4;                  // k sub-chunk 0..3
  const int rm   = lane & 15;

#define STAGE(buf, kk0)                                                              \
  {                                                                                  \
    _Pragma("unroll")                                                                \
    for (int t = 0; t < 4; ++t) {                                                    \
      int r0 = wave * 32 + t * 8;                                                    \
      const unsigned short* ga = A  + (size_t)(m0 + r0 + srow) * K + (kk0) + sch * 8;\
      const unsigned short* gb = Bt + (size_t)(n0 + r0 + srow) * K + (kk0) + sch * 8;\
      __builtin_amdgcn_global_load_lds(                                              \
          (const __attribute__((address_space(1))) unsigned int*)(const void*)ga,    \
          (__attribute__((address_space(3))) unsigned int*)(void*)&As[buf][r0 * 64], \
          16, 0, 0);                                                                 \
      __builtin_amdgcn_global_load_lds(                                              \
          (const __attribute__((address_space(1))) unsigned int*)(const void*)gb,    \
          (__attribute__((address_space(3))) unsigned int*)(void*)&Bs[buf][r0 * 64], \
          16, 0, 0);                                                                 \
    }                                                                                \
  }

  STAGE(0, 0);
  int cur = 0;
  for (int k0 = 0; k0 < K; k0 += 64) {
    if (k0 + 64 < K) {
      STAGE(cur ^ 1, k0 + 64);                 // prefetch next tile
      asm volatile("s_waitcnt vmcnt(8)" ::: "memory");   // current tile landed
    } else {
      asm volatile("s_waitcnt vmcnt(0)" ::: "memory");
    }
    __builtin_amdgcn_s_barrier();              // all waves' current loads done
#pragma unroll
    for (int kk = 0; kk < 2; ++kk) {
      bf16x8 af[4], bfr[4];
#pragma unroll
      for (int i = 0; i < 4; ++i) {
        int ra = wy * 64 + i * 16 + rm;
        int rb = wx * 64 + i * 16 + rm;
        af[i]  = *(const bf16x8*)&As[cur][ra * 64 + (((kk * 4 + q) ^ (ra & 7)) << 3)];
        bfr[i] = *(const bf16x8*)&Bs[cur][rb * 64 + (((kk * 4 + q) ^ (rb & 7)) << 3)];
      }
#pragma unroll
      for (int i = 0; i < 4; ++i)
#pragma unroll
        for (int j = 0; j < 4; ++j)
          acc[i][j] = __builtin_amdgcn_mfma_f32_16x16x32_bf16(af[i], bfr[j], acc[i][j], 0, 0, 0);
    }
    __builtin_amdgcn_s_barrier();              // reads done before next overwrite
    cur ^= 1;
  }
#undef STAGE

  const int q4 = (lane >> 4) * 4;
#pragma unroll
  for (int i = 0; i < 4; ++i) {
#pragma unroll
    for (int j = 0; j < 4; ++j) {
      int row = m0 + wy * 64 + i * 16 + q4;
      int col = n0 + wx * 64 + j * 16 + rm;
      float bv = bias[col];
#pragma unroll
      for (int v = 0; v < 4; ++v) {
        float val = fmaxf(acc[i][j][v] + bv, 0.f);
        if constexpr (OUT_BF16) Cb[(size_t)(row + v) * N + col] = f2b(val);
        else                    Cf[(size_t)(row + v) * N + col] = val;
      }
    }
  }
}

// ====== fused gemm2 + mlp3: out = relu(g1@w2t + b2) @ w3 + b3 ======
// 64-row m-tiles -> grid 128 (2x machine fill vs 64). 2-phase K-loop
// (K=1024), 6 staged loads/lane -> vmcnt(6). Epilogue stages the 64x128 g2
// tile (bf16, swizzled) into the dead As LDS, then a 4-deep MFMA chain
// against w3b [16][128] produces the final [64][9] f32 rows.
__global__ __launch_bounds__(256) void gemm2_fused(const unsigned short* __restrict__ A,
    const unsigned short* __restrict__ Bt, const unsigned short* __restrict__ w3b,
    const float* __restrict__ bias2, const float* __restrict__ b3,
    float* __restrict__ out) {
  __shared__ alignas(16) unsigned short As[2][64 * 64];
  __shared__ alignas(16) unsigned short Bs[2][128 * 64];
  const int tid = threadIdx.x;
  const int lane = tid & 63;
  const int wave = tid >> 6;
  const int wy = wave >> 1, wx = wave & 1;     // 2x2 wave grid: 32 rows x 64 cols
  const int m0 = blockIdx.x * 64;
  const int K = 1024;

  f32x4 acc[2][4];
  const f32x4 z = {0.f, 0.f, 0.f, 0.f};
#pragma unroll
  for (int i = 0; i < 2; ++i)
#pragma unroll
    for (int j = 0; j < 4; ++j) acc[i][j] = z;

  const int srow = lane >> 3;
  const int sch  = (lane & 7) ^ srow;
  const int q    = lane >> 4;
  const int rm   = lane & 15;

  // 6 loads per lane per tile: 2 A-steps (64 rows) + 4 B-steps (128 rows)
#define STAGE2(buf, kk0)                                                             \
  {                                                                                  \
    _Pragma("unroll")                                                                \
    for (int t = 0; t < 2; ++t) {                                                    \
      int r0 = wave * 16 + t * 8;                                                    \
      const unsigned short* ga = A + (size_t)(m0 + r0 + srow) * K + (kk0) + sch * 8; \
      __builtin_amdgcn_global_load_lds(                                              \
          (const __attribute__((address_space(1))) unsigned int*)(const void*)ga,    \
          (__attribute__((address_space(3))) unsigned int*)(void*)&As[buf][r0 * 64], \
          16, 0, 0);                                                                 \
    }                                                                                \
    _Pragma("unroll")                                                                \
    for (int t = 0; t < 4; ++t) {                                                    \
      int r0 = wave * 32 + t * 8;                                                    \
      const unsigned short* gb = Bt + (size_t)(r0 + srow) * K + (kk0) + sch * 8;     \
      __builtin_amdgcn_global_load_lds(                                              \
          (const __attribute__((address_space(1))) unsigned int*)(const void*)gb,    \
          (__attribute__((address_space(3))) unsigned int*)(void*)&Bs[buf][r0 * 64], \
          16, 0, 0);                                                                 \
    }                                                                                \
  }

  STAGE2(0, 0);
  int cur = 0;
  for (int k0 = 0; k0 < K; k0 += 64) {
    if (k0 + 64 < K) {
      STAGE2(cur ^ 1, k0 + 64);
      asm volatile("s_waitcnt vmcnt(6)" ::: "memory");
    } else {
      asm volatile("s_waitcnt vmcnt(0)" ::: "memory");
    }
    __builtin_amdgcn_s_barrier();
#pragma unroll
    for (int kk = 0; kk < 2; ++kk) {
      bf16x8 af[2], bfr[4];
#pragma unroll
      for (int i = 0; i < 2; ++i) {
        int ra = wy * 32 + i * 16 + rm;
        af[i] = *(const bf16x8*)&As[cur][ra * 64 + (((kk * 4 + q) ^ (ra & 7)) << 3)];
      }
#pragma unroll
      for (int j = 0; j < 4; ++j) {
        int rb = wx * 64 + j * 16 + rm;
        bfr[j] = *(const bf16x8*)&Bs[cur][rb * 64 + (((kk * 4 + q) ^ (rb & 7)) << 3)];
      }
#pragma unroll
      for (int i = 0; i < 2; ++i)
#pragma unroll
        for (int j = 0; j < 4; ++j)
          acc[i][j] = __builtin_amdgcn_mfma_f32_16x16x32_bf16(af[i], bfr[j], acc[i][j], 0, 0, 0);
    }
    __builtin_amdgcn_s_barrier();
    cur ^= 1;
  }
#undef STAGE2

  // ---- stage g2 = relu(acc + b2) into As (bf16 [64][128], oct-swizzled) ----
  unsigned short* gs = &As[0][0];                // 16 KB, dead after K loop
  const int q4 = q * 4;
#pragma unroll
  for (int i = 0; i < 2; ++i) {
#pragma unroll
    for (int j = 0; j < 4; ++j) {
      int cl = wx * 64 + j * 16 + rm;            // local col 0..127
      float bv = bias2[cl];
#pragma unroll
      for (int v = 0; v < 4; ++v) {
        int r = wy * 32 + i * 16 + q4 + v;       // local row 0..63
        float val = fmaxf(acc[i][j][v] + bv, 0.f);
        gs[r * 128 + ((((cl >> 3) ^ (r & 7)) << 3) | (cl & 7))] = f2b(val);
      }
    }
  }
  __syncthreads();

  // ---- mini-GEMM: out_tile[64][9] = g2 @ w3 + b3 (each wave: 1 m-tile) ----
  f32x4 a2 = z;
#pragma unroll
  for (int kt = 0; kt < 4; ++kt) {
    bf16x8 bW3 = *(const bf16x8*)&w3b[rm * 128 + kt * 32 + q * 8];
    int row = wave * 16 + rm;
    bf16x8 aG = *(const bf16x8*)&gs[row * 128 + (((kt * 4 + q) ^ (row & 7)) << 3)];
    a2 = __builtin_amdgcn_mfma_f32_16x16x32_bf16(aG, bW3, a2, 0, 0, 0);
  }
  if (rm < 9) {
    float bv = b3[rm];
#pragma unroll
    for (int v = 0; v < 4; ++v) {
      int row = m0 + wave * 16 + q4 + v;
      out[(size_t)row * 9 + rm] = a2[v] + bv;
    }
  }
}

// =========================== launch ===========================
extern "C" void kernel_launch(void* const* d_in, const int* in_sizes, int n_in,
                              void* d_out, int out_size, void* d_ws, size_t ws_size,
                              hipStream_t stream) {
  const float* x   = (const float*)d_in[0];
  const int*   ei  = (const int*)d_in[1];
  const float* W1  = (const float*)d_in[3];
  const float* as1 = (const float*)d_in[4];
  const float* ad1 = (const float*)d_in[5];
  const float* b1  = (const float*)d_in[6];
  const float* W2  = (const float*)d_in[7];
  const float* as2 = (const float*)d_in[8];
  const float* ad2 = (const float*)d_in[9];
  const float* b2  = (const float*)d_in[10];
  const float* W3  = (const float*)d_in[11];
  const float* as3 = (const float*)d_in[12];
  const float* ad3 = (const float*)d_in[13];
  const float* b3  = (const float*)d_in[14];
  const float* W4  = (const float*)d_in[15];
  const float* as4 = (const float*)d_in[16];
  const float* ad4 = (const float*)d_in[17];
  const float* b4  = (const float*)d_in[18];
  const float* lw1 = (const float*)d_in[19];
  const float* lb1 = (const float*)d_in[20];
  const float* lw2 = (const float*)d_in[21];
  const float* lb2 = (const float*)d_in[22];
  const float* lw3 = (const float*)d_in[23];
  const float* lb3 = (const float*)d_in[24];
  float* out = (float*)d_out;

  // workspace carve-up (bf16 stored as u16)
  unsigned short* f   = (unsigned short*)d_ws;            // [8192][4608] bf16
  unsigned short* w1t = f   + (size_t)NGRAPH * KP;        // [1024][4608] bf16
  unsigned short* w2t = w1t + (size_t)1024 * KP;          // [128][1024]  bf16
  unsigned short* g1  = w2t + (size_t)128 * 1024;         // [8192][1024] bf16
  // Wb lives in the old-g2 region (AFTER g1) so it survives gemm1's g1 write:
  // gemm2_fused reads w3b from it. ~16 KB of the 4 MB region.
  unsigned short* Wb  = g1 + (size_t)NGRAPH * 1024;

  prep_wb<<<1, 256, 0, stream>>>(W2, as2, ad2, W3, as3, ad3, W4, as4, ad4, lw3, Wb);
  tcast<true ><<<dim3(KP / 64, 1024 / 64), 256, 0, stream>>>(lw1, w1t, FDIM, 1024, KP);
  tcast<false><<<dim3(1024 / 64, 128 / 64), 256, 0, stream>>>(lw2, w2t, 1024, 128, 1024);

  gat_fused<<<NGRAPH, 64, 0, stream>>>(x, ei, W1, as1, ad1,
      b1, b2, b3, b4, Wb, f);

  mfma_gemm<true ><<<512, 256, 0, stream>>>(
      f, w1t, g1, nullptr, lb1, KP, 1024, 8);

  gemm2_fused<<<NGRAPH / 64, 256, 0, stream>>>(
      g1, w2t, Wb + 6144, lb2, lb3, out);
}